// Round 11
// baseline (7226.180 us; speedup 1.0000x reference)
//
#include <hip/hip_runtime.h>

#define V_SZ 32000
#define D_SZ 256
#define H_SZ 512
#define B_SZ 16
#define S_SZ 400
#define T_SZ 100
#define G4   2048
#define VX   32050
#define SENTU 0xFFFFFFFFu

typedef unsigned short ushort_t;
typedef __attribute__((ext_vector_type(8))) __bf16 bf16x8;
typedef __attribute__((ext_vector_type(8))) unsigned short ushort8_t;
typedef __attribute__((ext_vector_type(4))) float f32x4;
typedef __attribute__((ext_vector_type(4))) unsigned u32x4;

union UU { u32x4 q; bf16x8 v; };

__device__ __forceinline__ ushort_t f2bf(float x) {
  union { float f; unsigned u; } v; v.f = x;
  unsigned r = v.u + 0x7fffu + ((v.u >> 16) & 1u);
  return (ushort_t)(r >> 16);
}
__device__ __forceinline__ float bf2f(ushort_t x) {
  union { unsigned u; float f; } v; v.u = ((unsigned)x) << 16; return v.f;
}
__device__ __forceinline__ float bfu2f(unsigned x) {
  union { unsigned u; float f; } v; v.u = x << 16; return v.f;
}
__device__ __forceinline__ float u2f(unsigned x) {
  union { unsigned u; float f; } v; v.u = x; return v.f;
}
__device__ __forceinline__ float sigf(float x) { return 1.0f / (1.0f + __expf(-x)); }
__device__ __forceinline__ float tanh_f(float x) {
  float e = __expf(2.0f * x);
  return 1.0f - 2.0f / (e + 1.0f);
}
__device__ __forceinline__ float dot4(f32x4 a, f32x4 b) {
  return a.x * b.x + a.y * b.y + a.z * b.z + a.w * b.w;
}
// write-through store to the device coherence point (IC); cross-XCD safe.
__device__ __forceinline__ void stg(float* p, float v) {
  __hip_atomic_store(p, v, __ATOMIC_RELAXED, __HIP_MEMORY_SCOPE_AGENT);
}
__device__ __forceinline__ void stg_u32(unsigned* p, unsigned v) {
  __hip_atomic_store(p, v, __ATOMIC_RELAXED, __HIP_MEMORY_SCOPE_AGENT);
}
// physical XCD id [measured: learn_hip m09]
__device__ __forceinline__ int xcc_id() {
  unsigned v;
  asm volatile("s_getreg_b32 %0, hwreg(HW_REG_XCC_ID)" : "=s"(v));
  return (int)(v & 0xf);
}
__device__ __forceinline__ unsigned okq(u32x4 c) {
  return (unsigned)((c.x != SENTU) & (c.y != SENTU) & (c.z != SENTU) & (c.w != SENTU));
}
// single IC-coherent 16B load
__device__ __forceinline__ u32x4 ld1_ic(const unsigned* p) {
  u32x4 v;
  asm volatile("global_load_dwordx4 %0, %1, off sc0 sc1\n\ts_waitcnt vmcnt(0)"
               : "=&v"(v) : "v"(p) : "memory");
  return v;
}

// ---------------- f32 -> bf16 convert ----------------
__global__ __launch_bounds__(256) void cvt_kernel(const float* in, ushort_t* outp, int n) {
  int i = blockIdx.x * 256 + threadIdx.x;
  int stride = gridDim.x * 256;
  for (; i < n; i += stride) outp[i] = f2bf(in[i]);
}

// cols [0,256) of a row-stride-512 matrix -> packed bf16 (2048 x 256)
__global__ __launch_bounds__(256) void cvt_strided_kernel(const float* in, ushort_t* outp) {
  int gid = blockIdx.x * 256 + threadIdx.x;  // 524288
  int r = gid >> 8, d = gid & 255;
  outp[gid] = f2bf(in[(size_t)r * 512 + d]);
}

// wo2t[h][d] = wo2[d][h]  (512 x 256 bf16)
__global__ __launch_bounds__(256) void cvt_wo2t_kernel(const float* wo2, ushort_t* outp) {
  int gid = blockIdx.x * 256 + threadIdx.x;  // 131072
  int h = gid >> 8, d = gid & 255;
  outp[gid] = f2bf(wo2[(size_t)d * 512 + h]);
}

// Wfused[r][c] = sum_d dwih[r][256+d] * wo2[d][c]   (2048 x 512 f32)
__global__ __launch_bounds__(256) void wfused_kernel(const float* dwih, const float* wo2,
                                                     float* wf) {
  __shared__ float xr_s[256];
  int r = blockIdx.x;
  xr_s[threadIdx.x] = dwih[(size_t)r * 512 + 256 + threadIdx.x];
  __syncthreads();
  float a0 = 0, a1 = 0;
  for (int d = 0; d < 256; ++d) {
    float x = xr_s[d];
    a0 += x * wo2[(size_t)d * 512 + threadIdx.x];
    a1 += x * wo2[(size_t)d * 512 + threadIdx.x + 256];
  }
  wf[(size_t)r * 512 + threadIdx.x] = a0;
  wf[(size_t)r * 512 + threadIdx.x + 256] = a1;
}

// wfp[h] = sum_d wpgen[1280+d] * wo2[d][h]
__global__ __launch_bounds__(256) void wfp_kernel(const float* wpgen, const float* wo2,
                                                  float* wfp) {
  int h = blockIdx.x * 256 + threadIdx.x;
  float a = 0;
  for (int d = 0; d < 256; ++d) a += wpgen[1280 + d] * wo2[(size_t)d * 512 + h];
  wfp[h] = a;
}

// pack Whh (both dirs) into per-block wave-major bf16 rows
__global__ __launch_bounds__(256) void pack_whh_kernel(const float* whh_f, const float* whh_b,
                                                       ushort_t* outp) {
  int gid = blockIdx.x * 256 + threadIdx.x;  // 2*2048*512
  int col = gid & 511;
  int p_g = gid >> 9;
  int dir = p_g >> 11, p = p_g & 2047;
  int ub = p >> 6, g = (p >> 4) & 3, u = p & 15;
  const float* src = dir ? whh_b : whh_f;
  outp[gid] = f2bf(src[(size_t)(g * 512 + ub * 16 + u) * 512 + col]);
}

// pack decoder recurrent weights [Whh_dec | Wfused] (2048 x 1024 bf16)
__global__ __launch_bounds__(256) void pack_wdec_kernel(const float* dwhh, const float* wfused,
                                                        ushort_t* outp) {
  int gid = blockIdx.x * 256 + threadIdx.x;  // 2048*1024
  int col = gid & 1023;
  int p = gid >> 10;
  int ub = p >> 4, g = (p >> 2) & 3, u = p & 3;
  int row = g * 512 + ub * 4 + u;
  float v = (col < 512) ? dwhh[(size_t)row * 512 + col] : wfused[(size_t)row * 512 + (col - 512)];
  outp[gid] = f2bf(v);
}

// gxT[(t*2048 + r)*16 + b] = gx_dec[(t*16+b)*2048 + r]
__global__ __launch_bounds__(256) void gxT_kernel(const float* gx, float* gxT) {
  int t = blockIdx.y;
  int r = blockIdx.x * 256 + threadIdx.x;
  float v[16];
#pragma unroll
  for (int b = 0; b < 16; ++b) v[b] = gx[((size_t)t * 16 + b) * G4 + r];
  f32x4* dst = (f32x4*)(gxT + ((size_t)t * G4 + r) * 16);
#pragma unroll
  for (int q = 0; q < 4; ++q) {
    f32x4 w = {v[q * 4], v[q * 4 + 1], v[q * 4 + 2], v[q * 4 + 3]};
    dst[q] = w;
  }
}

// ---------------- gather embeddings (bf16) ----------------
__global__ __launch_bounds__(256) void gather_src_kernel(const ushort_t* emb_bf, const int* source,
                                                         ushort_t* xs_bf) {
  int gid = blockIdx.x * 256 + threadIdx.x;  // 204800
  int r = gid >> 5, e = gid & 31;
  int s = r >> 4, b = r & 15;
  int tok = source[b * S_SZ + s];
  ((ushort8_t*)xs_bf)[gid] = ((const ushort8_t*)emb_bf)[(size_t)tok * 32 + e];
}
__global__ __launch_bounds__(256) void gather_tgt_kernel(const ushort_t* emb_bf, const int* target,
                                                         ushort_t* xt_bf) {
  int gid = blockIdx.x * 256 + threadIdx.x;  // 51200
  int r = gid >> 5, e = gid & 31;
  int t = r >> 4, b = r & 15;
  int tok = target[b * T_SZ + t];
  ((ushort8_t*)xt_bf)[gid] = ((const ushort8_t*)emb_bf)[(size_t)tok * 32 + e];
}

// ---------------- MFMA helper: one wave computes a 16x64 tile of A(M,K) @ B(N,K)^T ------------
__device__ __forceinline__ void mfma_16x64(const ushort_t* A, const ushort_t* B_, int K,
                                           int m0, int n0, f32x4 acc[4]) {
  const int lane = threadIdx.x & 63;
  const int lr = lane & 15, kh = lane >> 4;
  const ushort_t* ap = A + (size_t)(m0 + lr) * K + kh * 8;
  const ushort_t* bp = B_ + (size_t)(n0 + lr) * K + kh * 8;
  for (int k0 = 0; k0 < K; k0 += 32) {
    bf16x8 av = *(const bf16x8*)(ap + k0);
#pragma unroll
    for (int s = 0; s < 4; ++s) {
      bf16x8 bv = *(const bf16x8*)(bp + (size_t)s * 16 * K + k0);
      acc[s] = __builtin_amdgcn_mfma_f32_16x16x32_bf16(av, bv, acc[s], 0, 0, 0);
    }
  }
}

// ---------------- gates GEMM: out[m][n] = A[m]·B[n] + bias[n], N=2048 ----------------
__global__ __launch_bounds__(256) void gemm_abt_bias(const ushort_t* A, const ushort_t* Bm,
                                                     const float* bias, float* out, int K) {
  int wave = threadIdx.x >> 6;
  int m0 = blockIdx.y * 16;
  int n0 = blockIdx.x * 256 + wave * 64;
  f32x4 acc[4] = {};
  mfma_16x64(A, Bm, K, m0, n0, acc);
  int lane = threadIdx.x & 63, lr = lane & 15, kh = lane >> 4;
#pragma unroll
  for (int s = 0; s < 4; ++s) {
    int n = n0 + s * 16 + lr;
    float bv = bias[n];
#pragma unroll
    for (int i = 0; i < 4; ++i) {
      int m = m0 + kh * 4 + i;
      out[(size_t)m * G4 + n] = acc[s][i] + bv;
    }
  }
}

// ---------------- enc_outs = ys_cat @ Wproj^T + bproj, out layout [b][s][h] ----------------
__global__ __launch_bounds__(256) void gemm_encout(const ushort_t* ys_cat, const ushort_t* wproj_bf,
                                                   const float* bproj, float* enc_outs) {
  int wave = threadIdx.x >> 6;
  int m0 = blockIdx.y * 16;
  int n0 = blockIdx.x * 256 + wave * 64;
  f32x4 acc[4] = {};
  mfma_16x64(ys_cat, wproj_bf, 2 * H_SZ, m0, n0, acc);
  int lane = threadIdx.x & 63, lr = lane & 15, kh = lane >> 4;
#pragma unroll
  for (int s = 0; s < 4; ++s) {
    int n = n0 + s * 16 + lr;
    float bv = bproj[n];
#pragma unroll
    for (int i = 0; i < 4; ++i) {
      int m = m0 + kh * 4 + i;
      int b = m & 15, si = m >> 4;
      enc_outs[((size_t)b * S_SZ + si) * H_SZ + n] = acc[s][i] + bv;
    }
  }
}

// ---------------- E2 = emb @ Wo2  (32000 x 512, bf16) ----------------
__global__ __launch_bounds__(256) void gemm_e2(const ushort_t* emb_bf, const ushort_t* wo2t_bf,
                                               ushort_t* e2) {
  int wave = threadIdx.x >> 6;
  int m0 = blockIdx.y * 16;
  int n0 = blockIdx.x * 256 + wave * 64;
  f32x4 acc[4] = {};
  mfma_16x64(emb_bf, wo2t_bf, 256, m0, n0, acc);
  int lane = threadIdx.x & 63, lr = lane & 15, kh = lane >> 4;
#pragma unroll
  for (int s = 0; s < 4; ++s) {
    int n = n0 + s * 16 + lr;
#pragma unroll
    for (int i = 0; i < 4; ++i) {
      int m = m0 + kh * 4 + i;
      e2[(size_t)m * 512 + n] = f2bf(acc[s][i]);
    }
  }
}

// ---------------- logits = tmp @ E2^T  (K=512), into d_out cols [0,V) ----------------
__global__ __launch_bounds__(256) void gemm_logits(const ushort_t* tmp_bf, const ushort_t* e2_bf,
                                                   float* out) {
  int wave = threadIdx.x >> 6;
  int m0 = blockIdx.x * 16;
  int n0 = blockIdx.y * 256 + wave * 64;
  f32x4 acc[4] = {};
  mfma_16x64(tmp_bf, e2_bf, 512, m0, n0, acc);
  int lane = threadIdx.x & 63, lr = lane & 15, kh = lane >> 4;
#pragma unroll
  for (int s = 0; s < 4; ++s) {
    int n = n0 + s * 16 + lr;
#pragma unroll
    for (int i = 0; i < 4; ++i) {
      int m = m0 + kh * 4 + i;
      out[(size_t)m * VX + n] = acc[s][i];
    }
  }
}

// ---------------- persistent bidirectional encoder LSTM (barrier-free, XCD-local) -----------
// 256 blocks, 100KB LDS => 1 block/CU => 32 blocks/XCD. Election: fwd on XCD0, bwd on XCD1.
// NO barriers/tags: producers fire-and-forget plain stores (write-through L1->L2) to hb plus
// an IC mirror (stg to hbM); consumers poll the DATA with batched sc0 dwordx4 loads and a
// sentinel check (h bf16 can never be 0xFFFF). Sticky timeout falls back to IC mirror polls.
__global__ __launch_bounds__(256, 1) void enc_kernel(const float* gx_f, const float* gx_b,
                                                     const ushort_t* whh_pk, const int* src_len,
                                                     unsigned* hb_f, unsigned* hb_b,
                                                     unsigned* hbM_f, unsigned* hbM_b,
                                                     unsigned* ys_cat_u32, float* h_final,
                                                     float* c_final, unsigned* ctrs) {
  __shared__ float big_s[25600];  // 100KB; forces 1 block/CU
  __shared__ int role_s;
  float* gates_s = big_s;
  const int tid = threadIdx.x;
  if (tid == 0) {
    int xcc = xcc_id();
    int r = -1;
    if (xcc == 0) {
      unsigned i = atomicAdd(&ctrs[0], 1u);
      if (i < 32u) r = (int)i;
    } else if (xcc == 1) {
      unsigned i = atomicAdd(&ctrs[32], 1u);
      if (i < 32u) r = 32 + (int)i;
    }
    role_s = r;
  }
  __syncthreads();
  const int role = role_s;
  if (role < 0) return;
  const int dir = role >> 5, ub = role & 31, j0 = ub * 16;
  const int g = tid >> 6, lane = tid & 63, lr = lane & 15, kh = lane >> 4;
  const float* gx = dir ? gx_b : gx_f;
  unsigned* hb = dir ? hb_b : hb_f;
  unsigned* hbM = dir ? hbM_b : hbM_f;
  const ushort_t* wrow =
      whh_pk + (size_t)(((dir * 32 + ub) * 4 + g) * 16 + lr) * 512 + kh * 8;
  const int bc = tid >> 4, uc = tid & 15;
  const int len_b = src_len[bc];
  float c_reg = 0.0f, h_reg = 0.0f;
  bool slow = false;

  // preload this wave's weight tile into registers (fixed for all steps)
  bf16x8 wv[16];
#pragma unroll
  for (int k = 0; k < 16; ++k) wv[k] = *(const bf16x8*)(wrow + k * 32);

  // maxlen = max over batch
  int maxlen;
  {
    int v = src_len[lane & 15];
    v = max(v, __shfl_xor(v, 1));
    v = max(v, __shfl_xor(v, 2));
    v = max(v, __shfl_xor(v, 4));
    v = max(v, __shfl_xor(v, 8));
    maxlen = v;
  }
  // zero-fill ys_cat for fully-masked positions s in [maxlen, S)
  for (int i = tid; i < (S_SZ - maxlen) * 128; i += 256) {
    int s = maxlen + (i >> 7);
    int r2 = i & 127;
    int bb = r2 >> 3, k = r2 & 7;
    ys_cat_u32[(size_t)(s * 16 + bb) * 512 + dir * 256 + (j0 >> 1) + k] = 0u;
  }

  // prefetch gx for t=0
  float gxa[4];
  {
    const int s0 = dir ? (maxlen - 1) : 0;
    const float* g0 = gx + (size_t)s0 * (16 * 2048) + g * 512 + j0 + lr;
#pragma unroll
    for (int i = 0; i < 4; ++i) gxa[i] = g0[(size_t)(kh * 4 + i) * 2048];
  }

  for (int t = 0; t < maxlen; ++t) {
    const int s_pos = dir ? (maxlen - 1 - t) : t;
    float gxn[4] = {0.f, 0.f, 0.f, 0.f};
    if (t + 1 < maxlen) {
      const int sn = dir ? (maxlen - 2 - t) : (t + 1);
      const float* gn = gx + (size_t)sn * (16 * 2048) + g * 512 + j0 + lr;
#pragma unroll
      for (int i = 0; i < 4; ++i) gxn[i] = gn[(size_t)(kh * 4 + i) * 2048];
    }
    // acquire h[t] via sentinel data-poll (t=0: zeros in registers)
    UU hv[16];
    if (t == 0) {
#pragma unroll
      for (int k = 0; k < 16; ++k) hv[k].q = (u32x4){0u, 0u, 0u, 0u};
    } else {
      const unsigned* hpL = hb + (size_t)t * 4096 + lr * 256 + kh * 4;
      const unsigned* hpM = hbM + (size_t)t * 4096 + lr * 256 + kh * 4;
      bool done = false;
      if (!slow) {
        for (int r3 = 0; r3 < 1500 && !done; ++r3) {
          asm volatile(
              "global_load_dwordx4 %0, %16, off sc0\n\t"
              "global_load_dwordx4 %1, %16, off offset:64 sc0\n\t"
              "global_load_dwordx4 %2, %16, off offset:128 sc0\n\t"
              "global_load_dwordx4 %3, %16, off offset:192 sc0\n\t"
              "global_load_dwordx4 %4, %16, off offset:256 sc0\n\t"
              "global_load_dwordx4 %5, %16, off offset:320 sc0\n\t"
              "global_load_dwordx4 %6, %16, off offset:384 sc0\n\t"
              "global_load_dwordx4 %7, %16, off offset:448 sc0\n\t"
              "global_load_dwordx4 %8, %16, off offset:512 sc0\n\t"
              "global_load_dwordx4 %9, %16, off offset:576 sc0\n\t"
              "global_load_dwordx4 %10, %16, off offset:640 sc0\n\t"
              "global_load_dwordx4 %11, %16, off offset:704 sc0\n\t"
              "global_load_dwordx4 %12, %16, off offset:768 sc0\n\t"
              "global_load_dwordx4 %13, %16, off offset:832 sc0\n\t"
              "global_load_dwordx4 %14, %16, off offset:896 sc0\n\t"
              "global_load_dwordx4 %15, %16, off offset:960 sc0\n\t"
              "s_waitcnt vmcnt(0)"
              : "=&v"(hv[0].q), "=&v"(hv[1].q), "=&v"(hv[2].q), "=&v"(hv[3].q),
                "=&v"(hv[4].q), "=&v"(hv[5].q), "=&v"(hv[6].q), "=&v"(hv[7].q),
                "=&v"(hv[8].q), "=&v"(hv[9].q), "=&v"(hv[10].q), "=&v"(hv[11].q),
                "=&v"(hv[12].q), "=&v"(hv[13].q), "=&v"(hv[14].q), "=&v"(hv[15].q)
              : "v"(hpL)
              : "memory");
          unsigned ok = 1;
#pragma unroll
          for (int k = 0; k < 16; ++k) ok &= okq(hv[k].q);
          if (__all((int)ok)) done = true;
          else __builtin_amdgcn_s_sleep(1);
        }
        if (!done) slow = true;  // sticky fallback
      }
      if (!done) {
        for (;;) {
          asm volatile(
              "global_load_dwordx4 %0, %16, off sc0 sc1\n\t"
              "global_load_dwordx4 %1, %16, off offset:64 sc0 sc1\n\t"
              "global_load_dwordx4 %2, %16, off offset:128 sc0 sc1\n\t"
              "global_load_dwordx4 %3, %16, off offset:192 sc0 sc1\n\t"
              "global_load_dwordx4 %4, %16, off offset:256 sc0 sc1\n\t"
              "global_load_dwordx4 %5, %16, off offset:320 sc0 sc1\n\t"
              "global_load_dwordx4 %6, %16, off offset:384 sc0 sc1\n\t"
              "global_load_dwordx4 %7, %16, off offset:448 sc0 sc1\n\t"
              "global_load_dwordx4 %8, %16, off offset:512 sc0 sc1\n\t"
              "global_load_dwordx4 %9, %16, off offset:576 sc0 sc1\n\t"
              "global_load_dwordx4 %10, %16, off offset:640 sc0 sc1\n\t"
              "global_load_dwordx4 %11, %16, off offset:704 sc0 sc1\n\t"
              "global_load_dwordx4 %12, %16, off offset:768 sc0 sc1\n\t"
              "global_load_dwordx4 %13, %16, off offset:832 sc0 sc1\n\t"
              "global_load_dwordx4 %14, %16, off offset:896 sc0 sc1\n\t"
              "global_load_dwordx4 %15, %16, off offset:960 sc0 sc1\n\t"
              "s_waitcnt vmcnt(0)"
              : "=&v"(hv[0].q), "=&v"(hv[1].q), "=&v"(hv[2].q), "=&v"(hv[3].q),
                "=&v"(hv[4].q), "=&v"(hv[5].q), "=&v"(hv[6].q), "=&v"(hv[7].q),
                "=&v"(hv[8].q), "=&v"(hv[9].q), "=&v"(hv[10].q), "=&v"(hv[11].q),
                "=&v"(hv[12].q), "=&v"(hv[13].q), "=&v"(hv[14].q), "=&v"(hv[15].q)
              : "v"(hpM)
              : "memory");
          unsigned ok = 1;
#pragma unroll
          for (int k = 0; k < 16; ++k) ok &= okq(hv[k].q);
          if (__all((int)ok)) break;
          __builtin_amdgcn_s_sleep(1);
        }
      }
    }
    f32x4 acc = {0.f, 0.f, 0.f, 0.f};
#pragma unroll
    for (int k = 0; k < 16; ++k)
      acc = __builtin_amdgcn_mfma_f32_16x16x32_bf16(hv[k].v, wv[k], acc, 0, 0, 0);
#pragma unroll
    for (int i = 0; i < 4; ++i)
      gates_s[(g * 16 + lr) * 17 + kh * 4 + i] = acc[i] + gxa[i];
    __syncthreads();
    // cell update: thread (bc, uc) owns unit j0+uc for batch row bc
    float gi = gates_s[uc * 17 + bc];
    float gf = gates_s[(16 + uc) * 17 + bc];
    float gg = gates_s[(32 + uc) * 17 + bc];
    float go = gates_s[(48 + uc) * 17 + bc];
    bool msk = s_pos < len_b;
    float cn = sigf(gf) * c_reg + sigf(gi) * tanh_f(gg);
    float hn = sigf(go) * tanh_f(cn);
    float hout = msk ? hn : h_reg;
    if (msk) c_reg = cn;
    h_reg = hout;
    unsigned hbits = (unsigned)f2bf(hout);
    unsigned hpart = __shfl_xor(hbits, 1);
    unsigned ybits = msk ? (unsigned)f2bf(hn) : 0u;
    unsigned ypart = __shfl_xor(ybits, 1);
    if ((uc & 1) == 0) {
      unsigned wv2 = hbits | (hpart << 16);
      size_t ix = (size_t)(t + 1) * 4096 + bc * 256 + ((j0 + uc) >> 1);
      hb[ix] = wv2;            // local (L2) publish, fire-and-forget
      stg_u32(&hbM[ix], wv2);  // IC mirror, fire-and-forget
      ys_cat_u32[(size_t)(s_pos * 16 + bc) * 512 + dir * 256 + ((j0 + uc) >> 1)] =
          ybits | (ypart << 16);
    }
    if (t == maxlen - 1) {
      h_final[dir * 8192 + bc * 512 + j0 + uc] = hout;
      c_final[dir * 8192 + bc * 512 + j0 + uc] = c_reg;
    }
    __syncthreads();  // protect gates_s for next step
#pragma unroll
    for (int i = 0; i < 4; ++i) gxa[i] = gxn[i];
  }
}

// ---------------- seq_mean ----------------
__global__ __launch_bounds__(256) void seqmean_kernel(const float* enc_outs, const int* src_len,
                                                      float* seq_mean) {
  int b = blockIdx.x >> 1;
  int j = (blockIdx.x & 1) * 256 + threadIdx.x;
  int L = src_len[b];
  float a = 0;
  for (int s = 0; s < L; ++s) a += enc_outs[((size_t)b * S_SZ + s) * H_SZ + j];
  seq_mean[b * 512 + j] = a / (float)L;
}

// ---------------- dec state init: h (bf16 packed) + c (f32) ----------------
__global__ __launch_bounds__(256) void init_state_kernel(const float* h_final, const float* c_final,
                                                         const float* w2h, const float* b2h,
                                                         const float* w2c, const float* b2c,
                                                         unsigned* h_u32, float* c_init) {
  int gid = blockIdx.x * 256 + threadIdx.x;  // 16384
  int half = gid >> 13;
  int idx = gid & 8191;
  int b = idx >> 9, j = idx & 511;
  const float* src = half ? c_final : h_final;
  const float* w = (half ? w2c : w2h) + (size_t)j * 1024;
  float acc = (half ? b2c : b2h)[j];
  const f32x4* s0 = (const f32x4*)(src + b * 512);
  const f32x4* s1 = (const f32x4*)(src + 8192 + b * 512);
  const f32x4* w0 = (const f32x4*)w;
  const f32x4* w1 = w0 + 128;
  float a = 0;
  for (int k = 0; k < 128; ++k) a += dot4(s0[k], w0[k]);
  for (int k = 0; k < 128; ++k) a += dot4(s1[k], w1[k]);
  acc += a;
  if (half) {
    c_init[idx] = acc;
  } else {
    unsigned bits = (unsigned)f2bf(acc);
    unsigned pb2 = __shfl_xor(bits, 1);
    if ((j & 1) == 0) h_u32[b * 256 + (j >> 1)] = bits | (pb2 << 16);
  }
}

// ---------------- tmp0 = tanh([dec_h | seq_mean] @ Wo1^T + bo1) -> tmp slot 0 (bf16) ---------
__global__ __launch_bounds__(256) void tmp0_kernel(const unsigned* h0_u32, const float* seq_mean,
                                                   const float* wo1, const float* bo1,
                                                   unsigned* tmp_u32) {
  int gid = blockIdx.x * 256 + threadIdx.x;  // 8192
  int b = gid >> 9, j = gid & 511;
  const f32x4* x1 = (const f32x4*)(seq_mean + b * 512);
  const f32x4* w0 = (const f32x4*)(wo1 + (size_t)j * 1024);
  const f32x4* w1 = w0 + 128;
  float a = bo1[j];
  float p = 0;
  const ushort_t* h0 = (const ushort_t*)(h0_u32) + b * 512;
  for (int k = 0; k < 128; ++k) {
    f32x4 hv = {bf2f(h0[k * 4]), bf2f(h0[k * 4 + 1]), bf2f(h0[k * 4 + 2]), bf2f(h0[k * 4 + 3])};
    p += dot4(hv, w0[k]);
  }
  for (int k = 0; k < 128; ++k) p += dot4(x1[k], w1[k]);
  float tv = tanh_f(a + p);
  unsigned bits = (unsigned)f2bf(tv);
  unsigned pb2 = __shfl_xor(bits, 1);
  if ((j & 1) == 0) tmp_u32[b * 256 + (j >> 1)] = bits | (pb2 << 16);
}

// ---------------- persistent decoder: barrier-free dataflow (batched sentinel polls) ---------
// PA polls h/tmp[t] (8x dwordx4 IC), PB wave0 polls h[t+1] (1x dwordx4), PC polls z/ctx/tmp
// (8 loads). All state write-once per step; producers fire-and-forget stg; no barriers.
// ctx_part layout: [((t*16+b)*512 + unit)*8 + chunk] so PC's 8 partials are 32 contiguous B.
__global__ __launch_bounds__(256) void dec_kernel(
    const ushort_t* xt_bf, const int* src_len, const ushort_t* wdec_pk,
    const float* wpgen, const float* bpgen, const float* wfp, const ushort_t* wo1_bf,
    const float* bo1, const float* enc_outs, const float* gxT, unsigned* h_u32,
    const float* c_init, unsigned* tmp_u32, float* ctx_part, float* z_part, float* zinv,
    float* pgen_o, float* pexp) {
  __shared__ ushort_t ec_s[50 * 512];  // 51.2 KB enc chunk (bf16)
  __shared__ float part_s[4 * 16 * 17];
  __shared__ f32x4 smem4[272];  // h_s(512) + ctx_s(512) + pad
  __shared__ float red_s[8];
  __shared__ float p_s[64];
  float* sm = (float*)smem4;

  const int blk = blockIdx.x, tid = threadIdx.x;
  const int w = tid >> 6, lane = tid & 63, lr = lane & 15, kh = lane >> 4;
  const int j0 = blk * 4;
  const ushort_t* wrow = wdec_pk + (size_t)(blk * 16 + lr) * 1024 + w * 256 + kh * 8;
  const int b_c = (tid >> 2) & 15, u_c = tid & 3;  // cell roles (tid<64)
  float c_reg = (tid < 64) ? c_init[b_c * 512 + j0 + u_c] : 0.0f;
  const int b_pb = blk >> 3, ch = blk & 7, s0c = ch * 50;
  const int len_pb = src_len[b_pb];
  const int nc = ch;

  // preload this wave's recurrent-weight tile
  bf16x8 wv[8];
#pragma unroll
  for (int k = 0; k < 8; ++k) wv[k] = *(const bf16x8*)(wrow + k * 32);

  // load enc chunk into LDS as bf16 (once)
  {
    const f32x4* ebase = (const f32x4*)(enc_outs + ((size_t)b_pb * S_SZ + s0c) * H_SZ);
    unsigned* dst = (unsigned*)ec_s;
    for (int i = tid; i < 6400; i += 256) {
      f32x4 v = ebase[i];
      dst[2 * i] = (unsigned)f2bf(v.x) | ((unsigned)f2bf(v.y) << 16);
      dst[2 * i + 1] = (unsigned)f2bf(v.z) | ((unsigned)f2bf(v.w) << 16);
    }
  }

  // prefetch gx for t=0 (coalesced gxT layout [t][row][b])
  float gxa[4] = {0.f, 0.f, 0.f, 0.f};
  if (tid < 64) {
#pragma unroll
    for (int g2 = 0; g2 < 4; ++g2)
      gxa[g2] = gxT[((size_t)(g2 * 512 + j0 + u_c)) * 16 + b_c];
  }

  for (int t = 0; t < T_SZ; ++t) {
    // ---------- PA: poll A operand (h for w<2, tmp for w>=2), then MFMA ----------
    {
      const unsigned* asrc = (w < 2) ? (h_u32 + (size_t)t * 4096) : (tmp_u32 + (size_t)t * 4096);
      const unsigned* hp = asrc + lr * 256 + (w & 1) * 128 + kh * 4;
      UU hv[8];
      for (;;) {
        asm volatile(
            "global_load_dwordx4 %0, %8, off sc0 sc1\n\t"
            "global_load_dwordx4 %1, %8, off offset:64 sc0 sc1\n\t"
            "global_load_dwordx4 %2, %8, off offset:128 sc0 sc1\n\t"
            "global_load_dwordx4 %3, %8, off offset:192 sc0 sc1\n\t"
            "global_load_dwordx4 %4, %8, off offset:256 sc0 sc1\n\t"
            "global_load_dwordx4 %5, %8, off offset:320 sc0 sc1\n\t"
            "global_load_dwordx4 %6, %8, off offset:384 sc0 sc1\n\t"
            "global_load_dwordx4 %7, %8, off offset:448 sc0 sc1\n\t"
            "s_waitcnt vmcnt(0)"
            : "=&v"(hv[0].q), "=&v"(hv[1].q), "=&v"(hv[2].q), "=&v"(hv[3].q),
              "=&v"(hv[4].q), "=&v"(hv[5].q), "=&v"(hv[6].q), "=&v"(hv[7].q)
            : "v"(hp)
            : "memory");
        unsigned ok = 1;
#pragma unroll
        for (int k = 0; k < 8; ++k) ok &= okq(hv[k].q);
        if (__all((int)ok)) break;
        __builtin_amdgcn_s_sleep(1);
      }
      f32x4 acc = {0.f, 0.f, 0.f, 0.f};
#pragma unroll
      for (int k = 0; k < 8; ++k)
        acc = __builtin_amdgcn_mfma_f32_16x16x32_bf16(hv[k].v, wv[k], acc, 0, 0, 0);
#pragma unroll
      for (int i = 0; i < 4; ++i) part_s[(w * 16 + lr) * 17 + kh * 4 + i] = acc[i];
      __syncthreads();
      if (tid < 64) {
        float gt[4];
#pragma unroll
        for (int g2 = 0; g2 < 4; ++g2) {
          int p = g2 * 4 + u_c;
          float a = gxa[g2];
#pragma unroll
          for (int w2 = 0; w2 < 4; ++w2) a += part_s[(w2 * 16 + p) * 17 + b_c];
          gt[g2] = a;
        }
        float cn = sigf(gt[1]) * c_reg + sigf(gt[0]) * tanh_f(gt[2]);
        c_reg = cn;
        float hn = sigf(gt[3]) * tanh_f(cn);
        unsigned bits = (unsigned)f2bf(hn);
        unsigned pb2 = __shfl_xor(bits, 1);
        if ((u_c & 1) == 0)
          stg_u32(&h_u32[(size_t)(t + 1) * 4096 + b_c * 256 + ((j0 + u_c) >> 1)],
                  bits | (pb2 << 16));
      }
      __syncthreads();  // part_s reuse next step
    }
    // ---------- PB: wave0 polls h[t+1], stages to sm; scores + partial ctx ----------
    {
      if (tid < 64 && t + 1 < T_SZ) {
#pragma unroll
        for (int g2 = 0; g2 < 4; ++g2)
          gxa[g2] = gxT[((size_t)(t + 1) * G4 + g2 * 512 + j0 + u_c) * 16 + b_c];
      }
      if (tid < 64) {
        const unsigned* hp = h_u32 + (size_t)(t + 1) * 4096 + b_pb * 256 + tid * 4;
        u32x4 v;
        for (;;) {
          v = ld1_ic(hp);
          if (__all((int)okq(v))) break;
          __builtin_amdgcn_s_sleep(1);
        }
        f32x4 h0 = {bfu2f(v.x & 0xffffu), bfu2f(v.x >> 16), bfu2f(v.y & 0xffffu),
                    bfu2f(v.y >> 16)};
        f32x4 h1 = {bfu2f(v.z & 0xffffu), bfu2f(v.z >> 16), bfu2f(v.w & 0xffffu),
                    bfu2f(v.w >> 16)};
        ((f32x4*)sm)[tid * 2] = h0;
        ((f32x4*)sm)[tid * 2 + 1] = h1;
      }
      __syncthreads();
      int st = tid >> 2, kq = tid & 3;
      if (st < 50) {
        const ushort8_t* er = (const ushort8_t*)(ec_s + st * 512) + kq * 16;
        const f32x4* hr = (const f32x4*)sm + kq * 32;
        float sc = 0;
#pragma unroll 4
        for (int k = 0; k < 16; ++k) {
          ushort8_t w8 = er[k];
          f32x4 w0 = {bf2f(w8[0]), bf2f(w8[1]), bf2f(w8[2]), bf2f(w8[3])};
          f32x4 w1 = {bf2f(w8[4]), bf2f(w8[5]), bf2f(w8[6]), bf2f(w8[7])};
          sc += dot4(hr[2 * k], w0) + dot4(hr[2 * k + 1], w1);
        }
        sc += __shfl_xor(sc, 1);
        sc += __shfl_xor(sc, 2);
        if (kq == 0) {
          int s_abs = s0c + st;
          float p = (s_abs < len_pb) ? __expf(sc) : 0.0f;
          p_s[st] = p;
          pexp[((size_t)t * 16 + b_pb) * S_SZ + s_abs] = p;
        }
      }
      __syncthreads();
      if (tid == 0) {
        float z = 0;
        for (int s = 0; s < 50; ++s) z += p_s[s];
        stg(&z_part[((size_t)t * 16 + b_pb) * 8 + ch], z);
      }
      float a0 = 0, a1 = 0;
      for (int s = 0; s < 50; ++s) {
        float p = p_s[s];
        a0 += p * bf2f(ec_s[s * 512 + tid]);
        a1 += p * bf2f(ec_s[s * 512 + tid + 256]);
      }
      float* cpb2 = ctx_part + ((size_t)t * 16 + b_pb) * 4096;
      stg(&cpb2[tid * 8 + ch], a0);
      stg(&cpb2[(tid + 256) * 8 + ch], a1);
    }
    // ---------- PC: poll z/ctx/tmp; combine + pgen + tmp[t+1] ----------
    {
      float* h_s = sm;
      float* ctx_s = sm + 512;
      const unsigned* pa = (const unsigned*)(ctx_part + ((size_t)t * 16 + b_pb) * 4096 +
                                             (size_t)tid * 8);
      const unsigned* pb2 = (const unsigned*)(ctx_part + ((size_t)t * 16 + b_pb) * 4096 +
                                              (size_t)(tid + 256) * 8);
      const unsigned* pz = (const unsigned*)(z_part + ((size_t)t * 16 + b_pb) * 8);
      const unsigned* pt = tmp_u32 + (size_t)t * 4096 + b_pb * 256 + (tid >> 1);
      u32x4 ca0, ca1, cb0, cb1, zq0, zq1;
      unsigned t0v, t1v;
      for (;;) {
        asm volatile(
            "global_load_dwordx4 %0, %8, off sc0 sc1\n\t"
            "global_load_dwordx4 %1, %8, off offset:16 sc0 sc1\n\t"
            "global_load_dwordx4 %2, %9, off sc0 sc1\n\t"
            "global_load_dwordx4 %3, %9, off offset:16 sc0 sc1\n\t"
            "global_load_dwordx4 %4, %10, off sc0 sc1\n\t"
            "global_load_dwordx4 %5, %10, off offset:16 sc0 sc1\n\t"
            "global_load_dword %6, %11, off sc0 sc1\n\t"
            "global_load_dword %7, %11, off offset:512 sc0 sc1\n\t"
            "s_waitcnt vmcnt(0)"
            : "=&v"(ca0), "=&v"(ca1), "=&v"(cb0), "=&v"(cb1), "=&v"(zq0), "=&v"(zq1),
              "=&v"(t0v), "=&v"(t1v)
            : "v"(pa), "v"(pb2), "v"(pz), "v"(pt)
            : "memory");
        unsigned ok = okq(ca0) & okq(ca1) & okq(cb0) & okq(cb1) & okq(zq0) & okq(zq1) &
                      (unsigned)((t0v != SENTU) & (t1v != SENTU));
        if (__all((int)ok)) break;
        __builtin_amdgcn_s_sleep(1);
      }
      float z = u2f(zq0.x) + u2f(zq0.y) + u2f(zq0.z) + u2f(zq0.w) + u2f(zq1.x) + u2f(zq1.y) +
                u2f(zq1.z) + u2f(zq1.w);
      float inv = 1.0f / z;
      float c0 = u2f(ca0.x) + u2f(ca0.y) + u2f(ca0.z) + u2f(ca0.w) + u2f(ca1.x) + u2f(ca1.y) +
                 u2f(ca1.z) + u2f(ca1.w);
      float c1 = u2f(cb0.x) + u2f(cb0.y) + u2f(cb0.z) + u2f(cb0.w) + u2f(cb1.x) + u2f(cb1.y) +
                 u2f(cb1.z) + u2f(cb1.w);
      ctx_s[tid] = c0 * inv;
      ctx_s[tid + 256] = c1 * inv;
      __syncthreads();
      float tp0 = bf2f((ushort_t)((tid & 1) ? (t0v >> 16) : (t0v & 0xffffu)));
      float tp1 = bf2f((ushort_t)((tid & 1) ? (t1v >> 16) : (t1v & 0xffffu)));
      float xe = bf2f(xt_bf[((size_t)t * 16 + b_pb) * 256 + tid]);
      float pg = wpgen[tid] * ctx_s[tid] + wpgen[tid + 256] * ctx_s[tid + 256] +
                 wpgen[512 + tid] * h_s[tid] + wpgen[512 + tid + 256] * h_s[tid + 256] +
                 wpgen[1024 + tid] * xe + wfp[tid] * tp0 + wfp[tid + 256] * tp1;
#pragma unroll
      for (int o = 32; o; o >>= 1) pg += __shfl_xor(pg, o);
      if (lane == 0) red_s[w] = pg;
      __syncthreads();
      if (nc == 0 && tid == 0) {
        pgen_o[t * 16 + b_pb] = sigf(red_s[0] + red_s[1] + red_s[2] + red_s[3] + bpgen[0]);
        zinv[t * 16 + b_pb] = inv;
      }
      int nidx = tid >> 2, kq = tid & 3;
      int n = nc * 64 + nidx;
      const ushort8_t* wrp = (const ushort8_t*)(wo1_bf + (size_t)n * 1024) + kq * 32;
      const f32x4* xr2 =
          (kq < 2) ? ((const f32x4*)h_s + kq * 64) : ((const f32x4*)ctx_s + (kq - 2) * 64);
      float a = 0;
#pragma unroll 4
      for (int k = 0; k < 32; ++k) {
        ushort8_t w8 = wrp[k];
        f32x4 w0 = {bf2f(w8[0]), bf2f(w8[1]), bf2f(w8[2]), bf2f(w8[3])};
        f32x4 w1 = {bf2f(w8[4]), bf2f(w8[5]), bf2f(w8[6]), bf2f(w8[7])};
        a += dot4(xr2[2 * k], w0) + dot4(xr2[2 * k + 1], w1);
      }
      a += __shfl_xor(a, 1);
      a += __shfl_xor(a, 2);
      float tv = tanh_f(a + bo1[n]);
      unsigned bits = (unsigned)f2bf(tv);
      unsigned pbits = __shfl_xor(bits, 4);
      if (kq == 0 && (nidx & 1) == 0)
        stg_u32(&tmp_u32[(size_t)(t + 1) * 4096 + b_pb * 256 + ((nc * 64 + nidx) >> 1)],
                bits | (pbits << 16));
      __syncthreads();  // protect sm for next step's PB staging
    }
  }
}

// ---------------- per (t,b) row softmax + copy-scatter + log ----------------
__global__ __launch_bounds__(1024) void finalize_kernel(float* out, const float* pexp,
                                                        const float* zinv, const float* pgen_i,
                                                        const int* src_ext) {
  __shared__ float scat[VX];
  __shared__ float red[64];
  const int row = blockIdx.x;
  const int b = row & 15;
  const int tid = threadIdx.x;
  for (int i = tid; i < VX; i += 1024) scat[i] = 0.0f;
  __syncthreads();
  const float pg = pgen_i[row];
  const float inv = zinv[row];
  if (tid < S_SZ) {
    float v = (1.0f - pg) * pexp[(size_t)row * S_SZ + tid] * inv;
    int col = src_ext[b * S_SZ + tid];
    atomicAdd(&scat[col], v);
  }
  float* orow = out + (size_t)row * VX;
  float l[32];
  float mx = -3.4e38f;
#pragma unroll
  for (int i2 = 0; i2 < 32; ++i2) {
    int col = tid + (i2 << 10);
    l[i2] = (col < V_SZ) ? orow[col] : -3.4e38f;
    mx = fmaxf(mx, l[i2]);
  }
#pragma unroll
  for (int o = 32; o; o >>= 1) mx = fmaxf(mx, __shfl_xor(mx, o));
  if ((tid & 63) == 0) red[16 + (tid >> 6)] = mx;
  __syncthreads();
  if (tid == 0) {
    float m2 = red[16];
    for (int w = 1; w < 16; ++w) m2 = fmaxf(m2, red[16 + w]);
    red[0] = m2;
  }
  __syncthreads();
  const float gmx = red[0];
  float se = 0.0f;
#pragma unroll
  for (int i2 = 0; i2 < 32; ++i2) {
    int col = tid + (i2 << 10);
    if (col < V_SZ) {
      l[i2] = __expf(l[i2] - gmx);
      se += l[i2];
    }
  }
#pragma unroll
  for (int o = 32; o; o >>= 1) se += __shfl_xor(se, o);
  if ((tid & 63) == 0) red[32 + (tid >> 6)] = se;
  __syncthreads();
  if (tid == 0) {
    float s2 = 0;
    for (int w = 0; w < 16; ++w) s2 += red[32 + w];
    red[1] = s2;
  }
  __syncthreads();
  const float scale = pg / red[1];
#pragma unroll
  for (int i2 = 0; i2 < 32; ++i2) {
    int col = tid + (i2 << 10);
    if (col < VX) {
      float base = (col < V_SZ) ? l[i2] * scale : 0.0f;
      orow[col] = __logf(base + scat[col] + 1e-20f);
    }
  }
}

extern "C" void kernel_launch(void* const* d_in, const int* in_sizes, int n_in, void* d_out,
                              int out_size, void* d_ws, size_t ws_size, hipStream_t stream) {
  (void)in_sizes; (void)n_in; (void)out_size; (void)ws_size;
  const int* source = (const int*)d_in[0];
  const int* source_ext = (const int*)d_in[1];
  const int* source_len = (const int*)d_in[2];
  const int* target = (const int*)d_in[3];
  const float* emb = (const float*)d_in[4];
  const float* wih_f = (const float*)d_in[5];
  const float* whh_f = (const float*)d_in[6];
  const float* b_f = (const float*)d_in[7];
  const float* wih_b = (const float*)d_in[8];
  const float* whh_b = (const float*)d_in[9];
  const float* b_b = (const float*)d_in[10];
  const float* wproj = (const float*)d_in[11];
  const float* bproj = (const float*)d_in[12];
  const float* w2h = (const float*)d_in[13];
  const float* b2h = (const float*)d_in[14];
  const float* w2c = (const float*)d_in[15];
  const float* b2c = (const float*)d_in[16];
  const float* wo1 = (const float*)d_in[17];
  const float* bo1 = (const float*)d_in[18];
  const float* wo2 = (const float*)d_in[19];
  const float* dwih = (const float*)d_in[20];
  const float* dwhh = (const float*)d_in[21];
  const float* dbias = (const float*)d_in[22];
  const float* wpgen = (const float*)d_in[23];
  const float* bpgen = (const float*)d_in[24];
  float* out = (float*)d_out;

  size_t off = 0;
  char* wsb = (char*)d_ws;
  auto alloc = [&](size_t bytes) -> void* {
    void* p = wsb + off;
    off += (bytes + 255) & ~(size_t)255;
    return p;
  };
  unsigned* ctrs = (unsigned*)alloc(4096);  // election counters: [0]=fwd, [32]=bwd
  ushort_t* emb_bf = (ushort_t*)alloc((size_t)V_SZ * D_SZ * 2);
  ushort_t* wihf_bf = (ushort_t*)alloc((size_t)G4 * D_SZ * 2);
  ushort_t* wihb_bf = (ushort_t*)alloc((size_t)G4 * D_SZ * 2);
  ushort_t* wihd_bf = (ushort_t*)alloc((size_t)G4 * D_SZ * 2);
  ushort_t* wproj_bf = (ushort_t*)alloc((size_t)H_SZ * 2 * H_SZ * 2);
  ushort_t* wo2t_bf = (ushort_t*)alloc((size_t)H_SZ * D_SZ * 2);
  ushort_t* wo1_bf = (ushort_t*)alloc((size_t)H_SZ * 1024 * 2);
  float* wfused = (float*)alloc((size_t)G4 * H_SZ * 4);
  float* wfp = (float*)alloc(512 * 4);
  ushort_t* whh_pk = (ushort_t*)alloc((size_t)2 * G4 * H_SZ * 2);
  ushort_t* wdec_pk = (ushort_t*)alloc((size_t)G4 * 1024 * 2);
  ushort_t* xs_bf = (ushort_t*)alloc((size_t)S_SZ * B_SZ * D_SZ * 2);
  ushort_t* xt_bf = (ushort_t*)alloc((size_t)T_SZ * B_SZ * D_SZ * 2);
  float* gx_f = (float*)alloc((size_t)S_SZ * B_SZ * G4 * 4);  // aliased by e2_bf after enc
  float* gx_b = (float*)alloc((size_t)S_SZ * B_SZ * G4 * 4);  // aliased by gx_dec/ctx_part/gxT
  unsigned* hb_f = (unsigned*)alloc((size_t)(S_SZ + 1) * 4096 * 4);
  unsigned* hb_b = (unsigned*)alloc((size_t)(S_SZ + 1) * 4096 * 4);
  unsigned* hbM_f = (unsigned*)alloc((size_t)(S_SZ + 1) * 4096 * 4);
  unsigned* hbM_b = (unsigned*)alloc((size_t)(S_SZ + 1) * 4096 * 4);
  unsigned* ys_cat_u32 = (unsigned*)alloc((size_t)S_SZ * B_SZ * 512 * 4);
  float* h_final = (float*)alloc((size_t)2 * B_SZ * H_SZ * 4);
  float* c_final = (float*)alloc((size_t)2 * B_SZ * H_SZ * 4);
  float* enc_outs = (float*)alloc((size_t)B_SZ * S_SZ * H_SZ * 4);
  float* seq_mean = (float*)alloc((size_t)B_SZ * H_SZ * 4);
  unsigned* h_u32 = (unsigned*)alloc((size_t)(T_SZ + 1) * 4096 * 4);
  float* c_init = (float*)alloc((size_t)B_SZ * H_SZ * 4);
  unsigned* tmp_u32 = (unsigned*)alloc((size_t)(T_SZ + 1) * 4096 * 4);
  float* z_part = (float*)alloc((size_t)T_SZ * B_SZ * 8 * 4);
  float* zinv = (float*)alloc((size_t)T_SZ * B_SZ * 4);
  float* pgen_b = (float*)alloc((size_t)T_SZ * B_SZ * 4);
  float* pexp = (float*)alloc((size_t)T_SZ * B_SZ * S_SZ * 4);
  // aliases into dead-after-encoder regions (gx_b = 13,107,200 floats)
  ushort_t* e2_bf = (ushort_t*)gx_f;                     // 32.8 MB
  float* gx_dec = gx_b;                                  // 3,276,800 floats
  float* ctx_part = gx_b + (size_t)3276800;              // 6,553,600 floats
  float* gxT = gx_b + (size_t)9830400;                   // 3,276,800 floats

  // sentinel pre-fills + election counters (stream-ordered before their producers)
  hipMemsetAsync(ctrs, 0, 4096, stream);
  hipMemsetAsync(hb_f, 0xFF, (size_t)(S_SZ + 1) * 4096 * 4, stream);   // slot0 never polled
  hipMemsetAsync(hb_b, 0xFF, (size_t)(S_SZ + 1) * 4096 * 4, stream);
  hipMemsetAsync(hbM_f, 0xFF, (size_t)(S_SZ + 1) * 4096 * 4, stream);
  hipMemsetAsync(hbM_b, 0xFF, (size_t)(S_SZ + 1) * 4096 * 4, stream);
  hipMemsetAsync(h_u32, 0xFF, (size_t)(T_SZ + 1) * 4096 * 4, stream);  // slot0 by init_state
  hipMemsetAsync(tmp_u32, 0xFF, (size_t)(T_SZ + 1) * 4096 * 4, stream);  // slot0 by tmp0
  hipMemsetAsync(z_part, 0xFF, (size_t)T_SZ * B_SZ * 8 * 4, stream);

  cvt_kernel<<<2048, 256, 0, stream>>>(emb, emb_bf, V_SZ * D_SZ);
  cvt_kernel<<<2048, 256, 0, stream>>>(wih_f, wihf_bf, G4 * D_SZ);
  cvt_kernel<<<2048, 256, 0, stream>>>(wih_b, wihb_bf, G4 * D_SZ);
  cvt_kernel<<<2048, 256, 0, stream>>>(wproj, wproj_bf, H_SZ * 2 * H_SZ);
  cvt_kernel<<<2048, 256, 0, stream>>>(wo1, wo1_bf, H_SZ * 1024);
  cvt_strided_kernel<<<2048, 256, 0, stream>>>(dwih, wihd_bf);
  cvt_wo2t_kernel<<<512, 256, 0, stream>>>(wo2, wo2t_bf);
  wfused_kernel<<<2048, 256, 0, stream>>>(dwih, wo2, wfused);
  wfp_kernel<<<2, 256, 0, stream>>>(wpgen, wo2, wfp);
  pack_whh_kernel<<<8192, 256, 0, stream>>>(whh_f, whh_b, whh_pk);
  pack_wdec_kernel<<<8192, 256, 0, stream>>>(dwhh, wfused, wdec_pk);
  gather_src_kernel<<<800, 256, 0, stream>>>(emb_bf, source, xs_bf);
  gather_tgt_kernel<<<200, 256, 0, stream>>>(emb_bf, target, xt_bf);
  gemm_abt_bias<<<dim3(8, 400), 256, 0, stream>>>(xs_bf, wihf_bf, b_f, gx_f, 256);
  gemm_abt_bias<<<dim3(8, 400), 256, 0, stream>>>(xs_bf, wihb_bf, b_b, gx_b, 256);
  enc_kernel<<<256, 256, 0, stream>>>(gx_f, gx_b, whh_pk, source_len, hb_f, hb_b, hbM_f, hbM_b,
                                      ys_cat_u32, h_final, c_final, ctrs);
  gemm_encout<<<dim3(2, 400), 256, 0, stream>>>((const ushort_t*)ys_cat_u32, wproj_bf, bproj,
                                                enc_outs);
  seqmean_kernel<<<32, 256, 0, stream>>>(enc_outs, source_len, seq_mean);
  init_state_kernel<<<64, 256, 0, stream>>>(h_final, c_final, w2h, b2h, w2c, b2c, h_u32, c_init);
  tmp0_kernel<<<32, 256, 0, stream>>>(h_u32, seq_mean, wo1, bo1, tmp_u32);
  gemm_abt_bias<<<dim3(8, 100), 256, 0, stream>>>(xt_bf, wihd_bf, dbias, gx_dec, 256);
  gxT_kernel<<<dim3(8, 100), 256, 0, stream>>>(gx_dec, gxT);
  gemm_e2<<<dim3(2, 2000), 256, 0, stream>>>(emb_bf, wo2t_bf, e2_bf);
  // ctx_part aliases the (now dead) backward-gx region: sentinel-fill after enc, before dec
  hipMemsetAsync(ctx_part, 0xFF, (size_t)T_SZ * B_SZ * 8 * H_SZ * 4, stream);
  dec_kernel<<<128, 256, 0, stream>>>(xt_bf, source_len, wdec_pk, wpgen, bpgen, wfp, wo1_bf, bo1,
                                      enc_outs, gxT, h_u32, c_init, tmp_u32, ctx_part, z_part,
                                      zinv, pgen_b, pexp);
  gemm_logits<<<dim3(100, 125), 256, 0, stream>>>((const ushort_t*)(tmp_u32 + 4096), e2_bf, out);
  finalize_kernel<<<1600, 1024, 0, stream>>>(out, pexp, zinv, pgen_b, source_ext);
}

// Round 12
// 4316.925 us; speedup vs baseline: 1.6739x; 1.6739x over previous
//
#include <hip/hip_runtime.h>

#define V_SZ 32000
#define D_SZ 256
#define H_SZ 512
#define B_SZ 16
#define S_SZ 400
#define T_SZ 100
#define G4   2048
#define VX   32050
#define LINE 32  // words per 128B line
#define SENTU 0xFFFFFFFFu

typedef unsigned short ushort_t;
typedef __attribute__((ext_vector_type(8))) __bf16 bf16x8;
typedef __attribute__((ext_vector_type(8))) unsigned short ushort8_t;
typedef __attribute__((ext_vector_type(4))) float f32x4;
typedef __attribute__((ext_vector_type(4))) unsigned u32x4;

__device__ __forceinline__ ushort_t f2bf(float x) {
  union { float f; unsigned u; } v; v.f = x;
  unsigned r = v.u + 0x7fffu + ((v.u >> 16) & 1u);
  return (ushort_t)(r >> 16);
}
__device__ __forceinline__ float bf2f(ushort_t x) {
  union { unsigned u; float f; } v; v.u = ((unsigned)x) << 16; return v.f;
}
__device__ __forceinline__ float bfu2f(unsigned x) {
  union { unsigned u; float f; } v; v.u = x << 16; return v.f;
}
__device__ __forceinline__ float sigf(float x) { return 1.0f / (1.0f + __expf(-x)); }
__device__ __forceinline__ float tanh_f(float x) {
  float e = __expf(2.0f * x);
  return 1.0f - 2.0f / (e + 1.0f);
}
__device__ __forceinline__ float dot4(f32x4 a, f32x4 b) {
  return a.x * b.x + a.y * b.y + a.z * b.z + a.w * b.w;
}
// write-through store to device coherence point; readers cold-miss fresh data.
__device__ __forceinline__ void stg(float* p, float v) {
  __hip_atomic_store(p, v, __ATOMIC_RELAXED, __HIP_MEMORY_SCOPE_AGENT);
}
__device__ __forceinline__ void stg_u32(unsigned* p, unsigned v) {
  __hip_atomic_store(p, v, __ATOMIC_RELAXED, __HIP_MEMORY_SCOPE_AGENT);
}
__device__ __forceinline__ unsigned pollu(const unsigned* p) {
  return __hip_atomic_load(p, __ATOMIC_RELAXED, __HIP_MEMORY_SCOPE_AGENT);
}
__device__ __forceinline__ unsigned okq(u32x4 c) {
  return (unsigned)((c.x != SENTU) & (c.y != SENTU) & (c.z != SENTU) & (c.w != SENTU));
}
// IC-coherent, non-caching 16B load (sc0 sc1): safe for polling partial data
// without polluting this XCD's L2 with stale lines.
__device__ __forceinline__ u32x4 ld1_ic(const unsigned* p) {
  u32x4 v;
  asm volatile("global_load_dwordx4 %0, %1, off sc0 sc1\n\ts_waitcnt vmcnt(0)"
               : "=&v"(v) : "v"(p) : "memory");
  return v;
}

// Slot barrier: NO atomics. Block i fire-and-forget stores epoch pc to its own
// 128B line; every block polls all slots with one wave (up to 3 slots/lane).
__device__ __forceinline__ void slot_barrier(unsigned* slots, int myslot, int nslots,
                                             unsigned pc) {
  asm volatile("s_waitcnt vmcnt(0)" ::: "memory");
  __syncthreads();
  if (threadIdx.x == 0)
    __hip_atomic_store(&slots[myslot * LINE], pc, __ATOMIC_RELAXED, __HIP_MEMORY_SCOPE_AGENT);
  if (threadIdx.x < 64) {
    const int i0 = threadIdx.x, i1 = threadIdx.x + 64, i2 = threadIdx.x + 128;
    for (;;) {
      unsigned v0 = pc, v1 = pc, v2 = pc;
      if (i0 < nslots) v0 = pollu(&slots[i0 * LINE]);
      if (i1 < nslots) v1 = pollu(&slots[i1 * LINE]);
      if (i2 < nslots) v2 = pollu(&slots[i2 * LINE]);
      if (__all((v0 >= pc) & (v1 >= pc) & (v2 >= pc))) break;
      __builtin_amdgcn_s_sleep(1);
    }
  }
  __syncthreads();
}

// ---------------- f32 -> bf16 convert ----------------
__global__ __launch_bounds__(256) void cvt_kernel(const float* in, ushort_t* outp, int n) {
  int i = blockIdx.x * 256 + threadIdx.x;
  int stride = gridDim.x * 256;
  for (; i < n; i += stride) outp[i] = f2bf(in[i]);
}

// pack Whh (both dirs) into per-block wave-major bf16 rows
__global__ __launch_bounds__(256) void pack_whh_kernel(const float* whh_f, const float* whh_b,
                                                       ushort_t* outp) {
  int gid = blockIdx.x * 256 + threadIdx.x;  // 2*2048*512
  int col = gid & 511;
  int p_g = gid >> 9;
  int dir = p_g >> 11, p = p_g & 2047;
  int ub = p >> 6, g = (p >> 4) & 3, u = p & 15;
  const float* src = dir ? whh_b : whh_f;
  outp[gid] = f2bf(src[(size_t)(g * 512 + ub * 16 + u) * 512 + col]);
}

// gxT[(t*2048 + r)*16 + b] = gx_dec[(t*16+b)*2048 + r]
__global__ __launch_bounds__(256) void gxT_kernel(const float* gx, float* gxT) {
  int t = blockIdx.y;
  int r = blockIdx.x * 256 + threadIdx.x;
  float v[16];
#pragma unroll
  for (int b = 0; b < 16; ++b) v[b] = gx[((size_t)t * 16 + b) * G4 + r];
  f32x4* dst = (f32x4*)(gxT + ((size_t)t * G4 + r) * 16);
#pragma unroll
  for (int q = 0; q < 4; ++q) {
    f32x4 w = {v[q * 4], v[q * 4 + 1], v[q * 4 + 2], v[q * 4 + 3]};
    dst[q] = w;
  }
}

// ---------------- gather source embeddings (bf16) ----------------
__global__ __launch_bounds__(256) void gather_src_kernel(const ushort_t* emb_bf, const int* source,
                                                         ushort_t* xs_bf) {
  int gid = blockIdx.x * 256 + threadIdx.x;  // 204800
  int r = gid >> 5, e = gid & 31;
  int s = r >> 4, b = r & 15;
  int tok = source[b * S_SZ + s];
  ((ushort8_t*)xs_bf)[gid] = ((const ushort8_t*)emb_bf)[(size_t)tok * 32 + e];
}

// ---------------- MFMA helper: one wave computes a 16x64 tile of A(M,K) @ B(N,K)^T ------------
__device__ __forceinline__ void mfma_16x64(const ushort_t* A, const ushort_t* B_, int K,
                                           int m0, int n0, f32x4 acc[4]) {
  const int lane = threadIdx.x & 63;
  const int lr = lane & 15, kh = lane >> 4;
  const ushort_t* ap = A + (size_t)(m0 + lr) * K + kh * 8;
  const ushort_t* bp = B_ + (size_t)(n0 + lr) * K + kh * 8;
  for (int k0 = 0; k0 < K; k0 += 32) {
    bf16x8 av = *(const bf16x8*)(ap + k0);
#pragma unroll
    for (int s = 0; s < 4; ++s) {
      bf16x8 bv = *(const bf16x8*)(bp + (size_t)s * 16 * K + k0);
      acc[s] = __builtin_amdgcn_mfma_f32_16x16x32_bf16(av, bv, acc[s], 0, 0, 0);
    }
  }
}

// ---------------- gates GEMM: out[m][n] = A[m]·B[n] + bias[n], N=2048 ----------------
__global__ __launch_bounds__(256) void gemm_abt_bias(const ushort_t* A, const ushort_t* Bm,
                                                     const float* bias, float* out, int K) {
  int wave = threadIdx.x >> 6;
  int m0 = blockIdx.y * 16;
  int n0 = blockIdx.x * 256 + wave * 64;
  f32x4 acc[4] = {};
  mfma_16x64(A, Bm, K, m0, n0, acc);
  int lane = threadIdx.x & 63, lr = lane & 15, kh = lane >> 4;
#pragma unroll
  for (int s = 0; s < 4; ++s) {
    int n = n0 + s * 16 + lr;
    float bv = bias[n];
#pragma unroll
    for (int i = 0; i < 4; ++i) {
      int m = m0 + kh * 4 + i;
      out[(size_t)m * G4 + n] = acc[s][i] + bv;
    }
  }
}

// ---------------- enc_outs = ys_cat @ Wproj^T + bproj, out layout [b][s][h] ----------------
__global__ __launch_bounds__(256) void gemm_encout(const ushort_t* ys_cat, const ushort_t* wproj_bf,
                                                   const float* bproj, float* enc_outs) {
  int wave = threadIdx.x >> 6;
  int m0 = blockIdx.y * 16;
  int n0 = blockIdx.x * 256 + wave * 64;
  f32x4 acc[4] = {};
  mfma_16x64(ys_cat, wproj_bf, 2 * H_SZ, m0, n0, acc);
  int lane = threadIdx.x & 63, lr = lane & 15, kh = lane >> 4;
#pragma unroll
  for (int s = 0; s < 4; ++s) {
    int n = n0 + s * 16 + lr;
    float bv = bproj[n];
#pragma unroll
    for (int i = 0; i < 4; ++i) {
      int m = m0 + kh * 4 + i;
      int b = m & 15, si = m >> 4;
      enc_outs[((size_t)b * S_SZ + si) * H_SZ + n] = acc[s][i] + bv;
    }
  }
}

// ---------------- persistent bidirectional encoder LSTM + fused prep ----------------
// Blocks 0..63: round-8 recurrence (dir = blk>>5, ub = blk&31, slot barriers).
// Blocks 64..255 (192): independent prep pipeline (stage A -> 192-slot barrier -> stage B):
//   A: wo1/wihd/wo2t/wproj cvt, gather_tgt, wfp, wfused
//   B: pack_wdec (needs wfused), gemm_e2 (needs wo2t)
__global__ __launch_bounds__(256) void enc_kernel(
    const float* gx_f, const float* gx_b, const ushort_t* whh_pk, const int* src_len,
    unsigned* hbf_f, unsigned* hbf_b, unsigned* ys_cat_u32, float* h_final, float* c_final,
    unsigned* ctrs,
    // prep inputs/outputs
    const int* target, const ushort_t* emb_bf, ushort_t* xt_bf, const float* wo1,
    ushort_t* wo1_bf, const float* dwih, ushort_t* wihd_bf, const float* wo2,
    ushort_t* wo2t_bf, const float* wproj, ushort_t* wproj_bf, const float* wpgen, float* wfp,
    float* wfused, const float* dwhh, ushort_t* wdec_pk, ushort_t* e2_bf) {
  __shared__ float gates_s[4 * 16 * 17];
  __shared__ float xr_s[256];
  const int blk = blockIdx.x, tid = threadIdx.x;

  if (blk >= 64) {
    // ---------------- prep pipeline ----------------
    const int pid = blk - 64;  // 0..191
    const int gtid = pid * 256 + tid;
    const int GSTR = 192 * 256;
    // stage A
    for (int i = gtid; i < 512 * 1024; i += GSTR) wo1_bf[i] = f2bf(wo1[i]);
    for (int i = gtid; i < 2048 * 256; i += GSTR) {
      int r = i >> 8, d = i & 255;
      wihd_bf[i] = f2bf(dwih[(size_t)r * 512 + d]);
    }
    for (int i = gtid; i < 512 * 256; i += GSTR) {
      int h2 = i >> 8, d2 = i & 255;
      wo2t_bf[i] = f2bf(wo2[(size_t)d2 * 512 + h2]);
    }
    for (int i = gtid; i < 512 * 1024; i += GSTR) wproj_bf[i] = f2bf(wproj[i]);
    for (int i = gtid; i < 51200; i += GSTR) {
      int r = i >> 5, e = i & 31;
      int tt = r >> 4, bb = r & 15;
      int tok = target[bb * T_SZ + tt];
      ((ushort8_t*)xt_bf)[i] = ((const ushort8_t*)emb_bf)[(size_t)tok * 32 + e];
    }
    for (int h2 = gtid; h2 < 512; h2 += GSTR) {
      float a = 0;
      for (int d = 0; d < 256; ++d) a += wpgen[1280 + d] * wo2[(size_t)d * 512 + h2];
      wfp[h2] = a;
    }
    for (int r = pid; r < 2048; r += 192) {
      xr_s[tid] = dwih[(size_t)r * 512 + 256 + tid];
      __syncthreads();
      float a0 = 0, a1 = 0;
      for (int d = 0; d < 256; ++d) {
        float x = xr_s[d];
        a0 += x * wo2[(size_t)d * 512 + tid];
        a1 += x * wo2[(size_t)d * 512 + tid + 256];
      }
      wfused[(size_t)r * 512 + tid] = a0;
      wfused[(size_t)r * 512 + tid + 256] = a1;
      __syncthreads();
    }
    slot_barrier(ctrs + 2048, pid, 192, 1u);
    // stage B
    for (int i = gtid; i < 2048 * 1024; i += GSTR) {
      int col = i & 1023, p = i >> 10;
      int ub2 = p >> 4, g2 = (p >> 2) & 3, u2 = p & 3;
      int row = g2 * 512 + ub2 * 4 + u2;
      float v = (col < 512) ? dwhh[(size_t)row * 512 + col]
                            : wfused[(size_t)row * 512 + (col - 512)];
      wdec_pk[i] = f2bf(v);
    }
    for (int q = pid; q < 4000; q += 192) {
      int mt = q >> 1, xt2 = q & 1;
      int wave = tid >> 6;
      int m0 = mt * 16, n0 = xt2 * 256 + wave * 64;
      f32x4 acc[4] = {};
      mfma_16x64(emb_bf, wo2t_bf, 256, m0, n0, acc);
      int lane2 = tid & 63, lr2 = lane2 & 15, kh2 = lane2 >> 4;
#pragma unroll
      for (int s = 0; s < 4; ++s) {
        int n = n0 + s * 16 + lr2;
#pragma unroll
        for (int i = 0; i < 4; ++i) {
          int m = m0 + kh2 * 4 + i;
          e2_bf[(size_t)m * 512 + n] = f2bf(acc[s][i]);
        }
      }
    }
    return;
  }

  // ---------------- recurrence (round-8) ----------------
  const int dir = blk >> 5, ub = blk & 31, j0 = ub * 16;
  const int g = tid >> 6, lane = tid & 63, lr = lane & 15, kh = lane >> 4;
  const float* gx = dir ? gx_b : gx_f;
  unsigned* hb = dir ? hbf_b : hbf_f;
  unsigned* slots = ctrs + dir * 1024;
  const ushort_t* wrow =
      whh_pk + (size_t)(((dir * 32 + ub) * 4 + g) * 16 + lr) * 512 + kh * 8;
  const int bc = tid >> 4, uc = tid & 15;
  const int len_b = src_len[bc];
  float c_reg = 0.0f, h_reg = 0.0f;

  int maxlen;
  {
    int v = src_len[lane & 15];
    v = max(v, __shfl_xor(v, 1));
    v = max(v, __shfl_xor(v, 2));
    v = max(v, __shfl_xor(v, 4));
    v = max(v, __shfl_xor(v, 8));
    maxlen = v;
  }
  for (int i = tid; i < (S_SZ - maxlen) * 128; i += 256) {
    int s = maxlen + (i >> 7);
    int r = i & 127;
    int bb = r >> 3, k = r & 7;
    ys_cat_u32[(size_t)(s * 16 + bb) * 512 + dir * 256 + (j0 >> 1) + k] = 0u;
  }

  float gxa[4];
  {
    const int s0 = dir ? (maxlen - 1) : 0;
    const float* g0 = gx + (size_t)s0 * (16 * 2048) + g * 512 + j0 + lr;
#pragma unroll
    for (int i = 0; i < 4; ++i) gxa[i] = g0[(size_t)(kh * 4 + i) * 2048];
  }

  for (int t = 0; t < maxlen; ++t) {
    const int s_pos = dir ? (maxlen - 1 - t) : t;
    float gxn[4] = {0.f, 0.f, 0.f, 0.f};
    if (t + 1 < maxlen) {
      const int sn = dir ? (maxlen - 2 - t) : (t + 1);
      const float* gn = gx + (size_t)sn * (16 * 2048) + g * 512 + j0 + lr;
#pragma unroll
      for (int i = 0; i < 4; ++i) gxn[i] = gn[(size_t)(kh * 4 + i) * 2048];
    }
    f32x4 acc = {0.f, 0.f, 0.f, 0.f};
    const ushort_t* ap = (const ushort_t*)(hb + (size_t)t * 4096) + lr * 512 + kh * 8;
#pragma unroll
    for (int k0 = 0; k0 < 512; k0 += 32)
      acc = __builtin_amdgcn_mfma_f32_16x16x32_bf16(*(const bf16x8*)(ap + k0),
                                                    *(const bf16x8*)(wrow + k0), acc, 0, 0, 0);
#pragma unroll
    for (int i = 0; i < 4; ++i)
      gates_s[(g * 16 + lr) * 17 + kh * 4 + i] = acc[i] + gxa[i];
    __syncthreads();
    float gi = gates_s[uc * 17 + bc];
    float gf = gates_s[(16 + uc) * 17 + bc];
    float gg = gates_s[(32 + uc) * 17 + bc];
    float go = gates_s[(48 + uc) * 17 + bc];
    bool msk = s_pos < len_b;
    float cn = sigf(gf) * c_reg + sigf(gi) * tanh_f(gg);
    float hn = sigf(go) * tanh_f(cn);
    float hout = msk ? hn : h_reg;
    if (msk) c_reg = cn;
    h_reg = hout;
    unsigned hbits = (unsigned)f2bf(hout);
    unsigned hpart = __shfl_xor(hbits, 1);
    unsigned ybits = msk ? (unsigned)f2bf(hn) : 0u;
    unsigned ypart = __shfl_xor(ybits, 1);
    if ((uc & 1) == 0) {
      stg_u32(&hb[(size_t)(t + 1) * 4096 + bc * 256 + ((j0 + uc) >> 1)], hbits | (hpart << 16));
      ys_cat_u32[(size_t)(s_pos * 16 + bc) * 512 + dir * 256 + ((j0 + uc) >> 1)] =
          ybits | (ypart << 16);
    }
    if (t == maxlen - 1) {
      h_final[dir * 8192 + bc * 512 + j0 + uc] = hout;
      c_final[dir * 8192 + bc * 512 + j0 + uc] = c_reg;
    }
    if (t + 1 < maxlen) slot_barrier(slots, ub, 32, (unsigned)(t + 1));
#pragma unroll
    for (int i = 0; i < 4; ++i) gxa[i] = gxn[i];
  }
}

// ---------------- seq_mean ----------------
__global__ __launch_bounds__(256) void seqmean_kernel(const float* enc_outs, const int* src_len,
                                                      float* seq_mean) {
  int b = blockIdx.x >> 1;
  int j = (blockIdx.x & 1) * 256 + threadIdx.x;
  int L = src_len[b];
  float a = 0;
  for (int s = 0; s < L; ++s) a += enc_outs[((size_t)b * S_SZ + s) * H_SZ + j];
  seq_mean[b * 512 + j] = a / (float)L;
}

// ---------------- dec state init: h (bf16 packed) + c (f32) ----------------
__global__ __launch_bounds__(256) void init_state_kernel(const float* h_final, const float* c_final,
                                                         const float* w2h, const float* b2h,
                                                         const float* w2c, const float* b2c,
                                                         unsigned* h_u32, float* c_init) {
  int gid = blockIdx.x * 256 + threadIdx.x;  // 16384
  int half = gid >> 13;
  int idx = gid & 8191;
  int b = idx >> 9, j = idx & 511;
  const float* src = half ? c_final : h_final;
  const float* w = (half ? w2c : w2h) + (size_t)j * 1024;
  float acc = (half ? b2c : b2h)[j];
  const f32x4* s0 = (const f32x4*)(src + b * 512);
  const f32x4* s1 = (const f32x4*)(src + 8192 + b * 512);
  const f32x4* w0 = (const f32x4*)w;
  const f32x4* w1 = w0 + 128;
  float a = 0;
  for (int k = 0; k < 128; ++k) a += dot4(s0[k], w0[k]);
  for (int k = 0; k < 128; ++k) a += dot4(s1[k], w1[k]);
  acc += a;
  if (half) {
    c_init[idx] = acc;
  } else {
    unsigned bits = (unsigned)f2bf(acc);
    unsigned pb2 = __shfl_xor(bits, 1);
    if ((j & 1) == 0) h_u32[b * 256 + (j >> 1)] = bits | (pb2 << 16);
  }
}

// ---------------- tmp0 = tanh([dec_h | seq_mean] @ Wo1^T + bo1) -> tmp slot 0 (bf16) ---------
__global__ __launch_bounds__(256) void tmp0_kernel(const unsigned* h0_u32, const float* seq_mean,
                                                   const float* wo1, const float* bo1,
                                                   unsigned* tmp_u32) {
  int gid = blockIdx.x * 256 + threadIdx.x;  // 8192
  int b = gid >> 9, j = gid & 511;
  const f32x4* x1 = (const f32x4*)(seq_mean + b * 512);
  const f32x4* w0 = (const f32x4*)(wo1 + (size_t)j * 1024);
  const f32x4* w1 = w0 + 128;
  float a = bo1[j];
  float p = 0;
  const ushort_t* h0 = (const ushort_t*)(h0_u32) + b * 512;
  for (int k = 0; k < 128; ++k) {
    f32x4 hv = {bf2f(h0[k * 4]), bf2f(h0[k * 4 + 1]), bf2f(h0[k * 4 + 2]), bf2f(h0[k * 4 + 3])};
    p += dot4(hv, w0[k]);
  }
  for (int k = 0; k < 128; ++k) p += dot4(x1[k], w1[k]);
  float tv = tanh_f(a + p);
  unsigned bits = (unsigned)f2bf(tv);
  unsigned pb2 = __shfl_xor(bits, 1);
  if ((j & 1) == 0) tmp_u32[b * 256 + (j >> 1)] = bits | (pb2 << 16);
}

// ---------------- persistent decoder (round-8 core) + fused logits ----------------
// Blocks 0..127: PA -> global slot-barrier -> PB -> 8-slot group barrier -> PC -> global.
// Block 128: leader — sentinel-polls each step's tmp row (non-caching sc0 sc1), then tags.
// Blocks 129..253: logits workers — per t, wait tag, compute one 16x256 tile of
//   logits = tmp @ E2^T into d_out (plain loads: first touch is after-ready -> coherent).
__global__ __launch_bounds__(256) void dec_kernel(
    const ushort_t* xt_bf, const int* src_len, const ushort_t* wdec_pk,
    const float* wpgen, const float* bpgen, const float* wfp, const ushort_t* wo1_bf,
    const float* bo1, const float* enc_outs, const float* gxT, unsigned* h_u32,
    const float* c_init, unsigned* tmp_u32, float* ctx_part, float* z_part, float* zinv,
    float* pgen_o, float* pexp, unsigned* ctrs, const ushort_t* e2_bf, float* out) {
  __shared__ ushort_t ec_s[50 * 512];  // 51.2 KB enc chunk (bf16)
  __shared__ float part_s[4 * 16 * 17];
  __shared__ f32x4 smem4[272];  // h_s(512) + ctx_s(512) + pad
  __shared__ float red_s[8];
  __shared__ float p_s[64];
  float* sm = (float*)smem4;
  unsigned* gslots = ctrs + 8192;   // 128 slot lines, global dec barrier

  const int blk = blockIdx.x, tid = threadIdx.x;

  if (blk >= 128) {
    // ---------------- fused logits ----------------
    const int sp = blk - 128;
    unsigned* tags = ctrs + 16384;  // 100 lines
    if (sp == 0) {
      for (int t = 0; t < T_SZ; ++t) {
        if (tid < 64) {
          const unsigned* hp = tmp_u32 + (size_t)(t + 1) * 4096 + tid * 64;
          for (;;) {
            unsigned ok = 1;
#pragma unroll
            for (int k = 0; k < 16; ++k) ok &= okq(ld1_ic(hp + k * 4));
            if (__all((int)ok)) break;
            __builtin_amdgcn_s_sleep(8);
          }
          if (tid == 0) stg_u32(&tags[t * 32], 1u);
        }
        __syncthreads();
      }
    } else if (sp <= 125) {
      const ushort_t* tmp_bf2 = (const ushort_t*)(tmp_u32 + 4096);
      const int wave = tid >> 6;
      const int n0 = (sp - 1) * 256 + wave * 64;
      const int lane2 = tid & 63, lr2 = lane2 & 15, kh2 = lane2 >> 4;
      for (int t = 0; t < T_SZ; ++t) {
        if (tid < 64) {
          while (pollu(&tags[t * 32]) == 0u) __builtin_amdgcn_s_sleep(4);
        }
        __syncthreads();
        f32x4 acc[4] = {};
        mfma_16x64(tmp_bf2, e2_bf, 512, t * 16, n0, acc);
#pragma unroll
        for (int s = 0; s < 4; ++s) {
          int n = n0 + s * 16 + lr2;
#pragma unroll
          for (int i = 0; i < 4; ++i) {
            int m = t * 16 + kh2 * 4 + i;
            out[(size_t)m * VX + n] = acc[s][i];
          }
        }
      }
    }
    return;
  }

  // ---------------- decoder core (round-8) ----------------
  const int w = tid >> 6, lane = tid & 63, lr = lane & 15, kh = lane >> 4;
  const int j0 = blk * 4;
  const ushort_t* wrow = wdec_pk + (size_t)(blk * 16 + lr) * 1024 + w * 256 + kh * 8;
  const int b_c = (tid >> 2) & 15, u_c = tid & 3;  // cell roles (tid<64)
  float c_reg = (tid < 64) ? c_init[b_c * 512 + j0 + u_c] : 0.0f;
  const int b_pb = blk >> 3, ch = blk & 7, s0c = ch * 50;
  const int len_pb = src_len[b_pb];
  const int nc = ch;
  unsigned* grslots = ctrs + 12288 + b_pb * 256;  // 8 slot lines per batch group
  unsigned gpc = 0;

  {
    const f32x4* ebase = (const f32x4*)(enc_outs + ((size_t)b_pb * S_SZ + s0c) * H_SZ);
    unsigned* dst = (unsigned*)ec_s;
    for (int i = tid; i < 6400; i += 256) {
      f32x4 v = ebase[i];
      dst[2 * i] = (unsigned)f2bf(v.x) | ((unsigned)f2bf(v.y) << 16);
      dst[2 * i + 1] = (unsigned)f2bf(v.z) | ((unsigned)f2bf(v.w) << 16);
    }
  }

  float gxa[4] = {0.f, 0.f, 0.f, 0.f};
  if (tid < 64) {
#pragma unroll
    for (int g2 = 0; g2 < 4; ++g2)
      gxa[g2] = gxT[((size_t)(g2 * 512 + j0 + u_c)) * 16 + b_c];
  }

  for (int t = 0; t < T_SZ; ++t) {
    // ---------- PA: gates via MFMA (K=1024 split over 4 waves) ----------
    {
      f32x4 acc = {0.f, 0.f, 0.f, 0.f};
      const unsigned* asrc = (w < 2) ? (h_u32 + (size_t)t * 4096) : (tmp_u32 + (size_t)t * 4096);
      const ushort_t* ap = (const ushort_t*)asrc + lr * 512 + (w & 1) * 256 + kh * 8;
#pragma unroll
      for (int k0 = 0; k0 < 256; k0 += 32)
        acc = __builtin_amdgcn_mfma_f32_16x16x32_bf16(*(const bf16x8*)(ap + k0),
                                                      *(const bf16x8*)(wrow + k0), acc, 0, 0, 0);
#pragma unroll
      for (int i = 0; i < 4; ++i) part_s[(w * 16 + lr) * 17 + kh * 4 + i] = acc[i];
      __syncthreads();
      if (tid < 64) {
        float gt[4];
#pragma unroll
        for (int g2 = 0; g2 < 4; ++g2) {
          int p = g2 * 4 + u_c;
          float a = gxa[g2];
#pragma unroll
          for (int w2 = 0; w2 < 4; ++w2) a += part_s[(w2 * 16 + p) * 17 + b_c];
          gt[g2] = a;
        }
        float cn = sigf(gt[1]) * c_reg + sigf(gt[0]) * tanh_f(gt[2]);
        c_reg = cn;
        float hn = sigf(gt[3]) * tanh_f(cn);
        unsigned bits = (unsigned)f2bf(hn);
        unsigned pb2 = __shfl_xor(bits, 1);
        if ((u_c & 1) == 0)
          stg_u32(&h_u32[(size_t)(t + 1) * 4096 + b_c * 256 + ((j0 + u_c) >> 1)],
                  bits | (pb2 << 16));
      }
    }
    slot_barrier(gslots, blk, 128, ++gpc);
    // ---------- PB: scores + partial ctx from LDS chunk ----------
    {
      if (tid < 64 && t + 1 < T_SZ) {
#pragma unroll
        for (int g2 = 0; g2 < 4; ++g2)
          gxa[g2] = gxT[((size_t)(t + 1) * G4 + g2 * 512 + j0 + u_c) * 16 + b_c];
      }
      if (tid < 128) {
        unsigned v0 = h_u32[(size_t)(t + 1) * 4096 + b_pb * 256 + tid * 2];
        unsigned v1 = h_u32[(size_t)(t + 1) * 4096 + b_pb * 256 + tid * 2 + 1];
        f32x4 hv = {bfu2f(v0 & 0xffffu), bfu2f(v0 >> 16), bfu2f(v1 & 0xffffu), bfu2f(v1 >> 16)};
        ((f32x4*)sm)[tid] = hv;
      }
      __syncthreads();
      int st = tid >> 2, kq = tid & 3;
      if (st < 50) {
        const ushort8_t* er = (const ushort8_t*)(ec_s + st * 512) + kq * 16;
        const f32x4* hr = (const f32x4*)sm + kq * 32;
        float sc = 0;
#pragma unroll 4
        for (int k = 0; k < 16; ++k) {
          ushort8_t w8 = er[k];
          f32x4 w0 = {bf2f(w8[0]), bf2f(w8[1]), bf2f(w8[2]), bf2f(w8[3])};
          f32x4 w1 = {bf2f(w8[4]), bf2f(w8[5]), bf2f(w8[6]), bf2f(w8[7])};
          sc += dot4(hr[2 * k], w0) + dot4(hr[2 * k + 1], w1);
        }
        sc += __shfl_xor(sc, 1);
        sc += __shfl_xor(sc, 2);
        if (kq == 0) {
          int s_abs = s0c + st;
          float p = (s_abs < len_pb) ? __expf(sc) : 0.0f;
          p_s[st] = p;
          pexp[((size_t)t * 16 + b_pb) * S_SZ + s_abs] = p;
        }
      }
      __syncthreads();
      if (tid == 0) {
        float z = 0;
        for (int s = 0; s < 50; ++s) z += p_s[s];
        stg(&z_part[((size_t)t * 16 + b_pb) * 8 + ch], z);
      }
      float a0 = 0, a1 = 0;
      for (int s = 0; s < 50; ++s) {
        float p = p_s[s];
        a0 += p * bf2f(ec_s[s * 512 + tid]);
        a1 += p * bf2f(ec_s[s * 512 + tid + 256]);
      }
      float* cp = ctx_part + (((size_t)t * 16 + b_pb) * 8 + ch) * 512;
      stg(&cp[tid], a0);
      stg(&cp[tid + 256], a1);
    }
    slot_barrier(grslots, ch, 8, (unsigned)(t + 1));
    // ---------- PC: combine ctx + pgen + tmp (h staged in sm by PB) ----------
    {
      float* h_s = sm;
      float* ctx_s = sm + 512;
      const float* zp = z_part + ((size_t)t * 16 + b_pb) * 8;
      float z = 0;
#pragma unroll
      for (int c2 = 0; c2 < 8; ++c2) z += zp[c2];
      float inv = 1.0f / z;
      const float* cpb = ctx_part + ((size_t)t * 16 + b_pb) * 8 * 512;
      float c0 = 0, c1 = 0;
#pragma unroll
      for (int c2 = 0; c2 < 8; ++c2) {
        c0 += cpb[c2 * 512 + tid];
        c1 += cpb[c2 * 512 + tid + 256];
      }
      ctx_s[tid] = c0 * inv;
      ctx_s[tid + 256] = c1 * inv;
      __syncthreads();
      const ushort_t* tmpp = (const ushort_t*)(tmp_u32 + (size_t)t * 4096) + b_pb * 512;
      float tp0 = bf2f(tmpp[tid]);
      float tp1 = bf2f(tmpp[tid + 256]);
      float xe = bf2f(xt_bf[((size_t)t * 16 + b_pb) * 256 + tid]);
      float pg = wpgen[tid] * ctx_s[tid] + wpgen[tid + 256] * ctx_s[tid + 256] +
                 wpgen[512 + tid] * h_s[tid] + wpgen[512 + tid + 256] * h_s[tid + 256] +
                 wpgen[1024 + tid] * xe + wfp[tid] * tp0 + wfp[tid + 256] * tp1;
#pragma unroll
      for (int o = 32; o; o >>= 1) pg += __shfl_xor(pg, o);
      if (lane == 0) red_s[w] = pg;
      __syncthreads();
      if (nc == 0 && tid == 0) {
        pgen_o[t * 16 + b_pb] = sigf(red_s[0] + red_s[1] + red_s[2] + red_s[3] + bpgen[0]);
        zinv[t * 16 + b_pb] = inv;
      }
      int nidx = tid >> 2, kq = tid & 3;
      int n = nc * 64 + nidx;
      const ushort8_t* wrp = (const ushort8_t*)(wo1_bf + (size_t)n * 1024) + kq * 32;
      const f32x4* xr2 =
          (kq < 2) ? ((const f32x4*)h_s + kq * 64) : ((const f32x4*)ctx_s + (kq - 2) * 64);
      float a = 0;
#pragma unroll 4
      for (int k = 0; k < 32; ++k) {
        ushort8_t w8 = wrp[k];
        f32x4 w0 = {bf2f(w8[0]), bf2f(w8[1]), bf2f(w8[2]), bf2f(w8[3])};
        f32x4 w1 = {bf2f(w8[4]), bf2f(w8[5]), bf2f(w8[6]), bf2f(w8[7])};
        a += dot4(xr2[2 * k], w0) + dot4(xr2[2 * k + 1], w1);
      }
      a += __shfl_xor(a, 1);
      a += __shfl_xor(a, 2);
      float tv = tanh_f(a + bo1[n]);
      unsigned bits = (unsigned)f2bf(tv);
      unsigned pbits = __shfl_xor(bits, 4);
      if (kq == 0 && (nidx & 1) == 0)
        stg_u32(&tmp_u32[(size_t)(t + 1) * 4096 + b_pb * 256 + ((nc * 64 + nidx) >> 1)],
                bits | (pbits << 16));
    }
    if (t + 1 < T_SZ) slot_barrier(gslots, blk, 128, ++gpc);
  }
}

// ---------------- per (t,b) row softmax + copy-scatter + log ----------------
__global__ __launch_bounds__(1024) void finalize_kernel(float* out, const float* pexp,
                                                        const float* zinv, const float* pgen_i,
                                                        const int* src_ext) {
  __shared__ float scat[VX];
  __shared__ float red[64];
  const int row = blockIdx.x;
  const int b = row & 15;
  const int tid = threadIdx.x;
  for (int i = tid; i < VX; i += 1024) scat[i] = 0.0f;
  __syncthreads();
  const float pg = pgen_i[row];
  const float inv = zinv[row];
  if (tid < S_SZ) {
    float v = (1.0f - pg) * pexp[(size_t)row * S_SZ + tid] * inv;
    int col = src_ext[b * S_SZ + tid];
    atomicAdd(&scat[col], v);
  }
  float* orow = out + (size_t)row * VX;
  float l[32];
  float mx = -3.4e38f;
#pragma unroll
  for (int i2 = 0; i2 < 32; ++i2) {
    int col = tid + (i2 << 10);
    l[i2] = (col < V_SZ) ? orow[col] : -3.4e38f;
    mx = fmaxf(mx, l[i2]);
  }
#pragma unroll
  for (int o = 32; o; o >>= 1) mx = fmaxf(mx, __shfl_xor(mx, o));
  if ((tid & 63) == 0) red[16 + (tid >> 6)] = mx;
  __syncthreads();
  if (tid == 0) {
    float m2 = red[16];
    for (int w = 1; w < 16; ++w) m2 = fmaxf(m2, red[16 + w]);
    red[0] = m2;
  }
  __syncthreads();
  const float gmx = red[0];
  float se = 0.0f;
#pragma unroll
  for (int i2 = 0; i2 < 32; ++i2) {
    int col = tid + (i2 << 10);
    if (col < V_SZ) {
      l[i2] = __expf(l[i2] - gmx);
      se += l[i2];
    }
  }
#pragma unroll
  for (int o = 32; o; o >>= 1) se += __shfl_xor(se, o);
  if ((tid & 63) == 0) red[32 + (tid >> 6)] = se;
  __syncthreads();
  if (tid == 0) {
    float s2 = 0;
    for (int w = 0; w < 16; ++w) s2 += red[32 + w];
    red[1] = s2;
  }
  __syncthreads();
  const float scale = pg / red[1];
#pragma unroll
  for (int i2 = 0; i2 < 32; ++i2) {
    int col = tid + (i2 << 10);
    if (col < VX) {
      float base = (col < V_SZ) ? l[i2] * scale : 0.0f;
      orow[col] = __logf(base + scat[col] + 1e-20f);
    }
  }
}

extern "C" void kernel_launch(void* const* d_in, const int* in_sizes, int n_in, void* d_out,
                              int out_size, void* d_ws, size_t ws_size, hipStream_t stream) {
  (void)in_sizes; (void)n_in; (void)out_size; (void)ws_size;
  const int* source = (const int*)d_in[0];
  const int* source_ext = (const int*)d_in[1];
  const int* source_len = (const int*)d_in[2];
  const int* target = (const int*)d_in[3];
  const float* emb = (const float*)d_in[4];
  const float* wih_f = (const float*)d_in[5];
  const float* whh_f = (const float*)d_in[6];
  const float* b_f = (const float*)d_in[7];
  const float* wih_b = (const float*)d_in[8];
  const float* whh_b = (const float*)d_in[9];
  const float* b_b = (const float*)d_in[10];
  const float* wproj = (const float*)d_in[11];
  const float* bproj = (const float*)d_in[12];
  const float* w2h = (const float*)d_in[13];
  const float* b2h = (const float*)d_in[14];
  const float* w2c = (const float*)d_in[15];
  const float* b2c = (const float*)d_in[16];
  const float* wo1 = (const float*)d_in[17];
  const float* bo1 = (const float*)d_in[18];
  const float* wo2 = (const float*)d_in[19];
  const float* dwih = (const float*)d_in[20];
  const float* dwhh = (const float*)d_in[21];
  const float* dbias = (const float*)d_in[22];
  const float* wpgen = (const float*)d_in[23];
  const float* bpgen = (const float*)d_in[24];
  float* out = (float*)d_out;

  size_t off = 0;
  char* wsb = (char*)d_ws;
  auto alloc = [&](size_t bytes) -> void* {
    void* p = wsb + off;
    off += (bytes + 255) & ~(size_t)255;
    return p;
  };
  // ctrs words: [0..1024) encf slots, [1024..2048) encb, [2048..8192) prep slots(192),
  // [8192..12288) dec global slots(128), [12288..16384) dec group slots, [16384..19584) tags
  unsigned* ctrs = (unsigned*)alloc(80 * 1024);
  ushort_t* emb_bf = (ushort_t*)alloc((size_t)V_SZ * D_SZ * 2);
  ushort_t* wihf_bf = (ushort_t*)alloc((size_t)G4 * D_SZ * 2);
  ushort_t* wihb_bf = (ushort_t*)alloc((size_t)G4 * D_SZ * 2);
  ushort_t* wihd_bf = (ushort_t*)alloc((size_t)G4 * D_SZ * 2);
  ushort_t* wproj_bf = (ushort_t*)alloc((size_t)H_SZ * 2 * H_SZ * 2);
  ushort_t* wo2t_bf = (ushort_t*)alloc((size_t)H_SZ * D_SZ * 2);
  ushort_t* wo1_bf = (ushort_t*)alloc((size_t)H_SZ * 1024 * 2);
  float* wfused = (float*)alloc((size_t)G4 * H_SZ * 4);
  float* wfp = (float*)alloc(512 * 4);
  ushort_t* whh_pk = (ushort_t*)alloc((size_t)2 * G4 * H_SZ * 2);
  ushort_t* wdec_pk = (ushort_t*)alloc((size_t)G4 * 1024 * 2);
  ushort_t* xs_bf = (ushort_t*)alloc((size_t)S_SZ * B_SZ * D_SZ * 2);
  ushort_t* xt_bf = (ushort_t*)alloc((size_t)T_SZ * B_SZ * D_SZ * 2);
  ushort_t* e2_bf = (ushort_t*)alloc((size_t)V_SZ * H_SZ * 2);  // dedicated (32.8 MB)
  float* gx_f = (float*)alloc((size_t)S_SZ * B_SZ * G4 * 4);
  float* gx_b = (float*)alloc((size_t)S_SZ * B_SZ * G4 * 4);  // aliased post-enc
  unsigned* hbf_f = (unsigned*)alloc((size_t)(S_SZ + 1) * 4096 * 4);
  unsigned* hbf_b = (unsigned*)alloc((size_t)(S_SZ + 1) * 4096 * 4);
  unsigned* ys_cat_u32 = (unsigned*)alloc((size_t)S_SZ * B_SZ * 512 * 4);
  float* h_final = (float*)alloc((size_t)2 * B_SZ * H_SZ * 4);
  float* c_final = (float*)alloc((size_t)2 * B_SZ * H_SZ * 4);
  float* enc_outs = (float*)alloc((size_t)B_SZ * S_SZ * H_SZ * 4);
  float* seq_mean = (float*)alloc((size_t)B_SZ * H_SZ * 4);
  unsigned* h_u32 = (unsigned*)alloc((size_t)(T_SZ + 1) * 4096 * 4);
  float* c_init = (float*)alloc((size_t)B_SZ * H_SZ * 4);
  unsigned* tmp_u32 = (unsigned*)alloc((size_t)(T_SZ + 1) * 4096 * 4);
  float* z_part = (float*)alloc((size_t)T_SZ * B_SZ * 8 * 4);
  float* zinv = (float*)alloc((size_t)T_SZ * B_SZ * 4);
  float* pgen_b = (float*)alloc((size_t)T_SZ * B_SZ * 4);
  float* pexp = (float*)alloc((size_t)T_SZ * B_SZ * S_SZ * 4);
  // aliases into dead-after-encoder gx_b (13,107,200 floats)
  float* gx_dec = gx_b;                                  // 3,276,800 floats
  float* ctx_part = gx_b + (size_t)3276800;              // 6,553,600 floats
  float* gxT = gx_b + (size_t)9830400;                   // 3,276,800 floats

  hipMemsetAsync(ctrs, 0, 80 * 1024, stream);            // slots + tags
  hipMemsetAsync(tmp_u32, 0xFF, (size_t)(T_SZ + 1) * 4096 * 4, stream);  // sentinel (leader)
  hipMemsetAsync(hbf_f, 0, 4096 * 4, stream);            // enc h slot 0 (dir f)
  hipMemsetAsync(hbf_b, 0, 4096 * 4, stream);            // enc h slot 0 (dir b)

  cvt_kernel<<<2048, 256, 0, stream>>>(emb, emb_bf, V_SZ * D_SZ);
  cvt_kernel<<<2048, 256, 0, stream>>>(wih_f, wihf_bf, G4 * D_SZ);
  cvt_kernel<<<2048, 256, 0, stream>>>(wih_b, wihb_bf, G4 * D_SZ);
  pack_whh_kernel<<<8192, 256, 0, stream>>>(whh_f, whh_b, whh_pk);
  gather_src_kernel<<<800, 256, 0, stream>>>(emb_bf, source, xs_bf);
  gemm_abt_bias<<<dim3(8, 400), 256, 0, stream>>>(xs_bf, wihf_bf, b_f, gx_f, 256);
  gemm_abt_bias<<<dim3(8, 400), 256, 0, stream>>>(xs_bf, wihb_bf, b_b, gx_b, 256);
  enc_kernel<<<256, 256, 0, stream>>>(gx_f, gx_b, whh_pk, source_len, hbf_f, hbf_b, ys_cat_u32,
                                      h_final, c_final, ctrs, target, emb_bf, xt_bf, wo1, wo1_bf,
                                      dwih, wihd_bf, wo2, wo2t_bf, wproj, wproj_bf, wpgen, wfp,
                                      wfused, dwhh, wdec_pk, e2_bf);
  gemm_encout<<<dim3(2, 400), 256, 0, stream>>>((const ushort_t*)ys_cat_u32, wproj_bf, bproj,
                                                enc_outs);
  seqmean_kernel<<<32, 256, 0, stream>>>(enc_outs, source_len, seq_mean);
  init_state_kernel<<<64, 256, 0, stream>>>(h_final, c_final, w2h, b2h, w2c, b2c, h_u32, c_init);
  tmp0_kernel<<<32, 256, 0, stream>>>(h_u32, seq_mean, wo1, bo1, tmp_u32);
  gemm_abt_bias<<<dim3(8, 100), 256, 0, stream>>>(xt_bf, wihd_bf, dbias, gx_dec, 256);
  gxT_kernel<<<dim3(8, 100), 256, 0, stream>>>(gx_dec, gxT);
  dec_kernel<<<256, 256, 0, stream>>>(xt_bf, source_len, wdec_pk, wpgen, bpgen, wfp, wo1_bf, bo1,
                                      enc_outs, gxT, h_u32, c_init, tmp_u32, ctx_part, z_part,
                                      zinv, pgen_b, pexp, ctrs, e2_bf, out);
  finalize_kernel<<<1600, 1024, 0, stream>>>(out, pexp, zinv, pgen_b, source_ext);
}

// Round 14
// 4281.121 us; speedup vs baseline: 1.6879x; 1.0084x over previous
//
#include <hip/hip_runtime.h>

#define V_SZ 32000
#define D_SZ 256
#define H_SZ 512
#define B_SZ 16
#define S_SZ 400
#define T_SZ 100
#define G4   2048
#define VX   32050
#define LINE 32  // words per 128B line
#define SENTU 0xFFFFFFFFu

typedef unsigned short ushort_t;
typedef __attribute__((ext_vector_type(8))) __bf16 bf16x8;
typedef __attribute__((ext_vector_type(8))) unsigned short ushort8_t;
typedef __attribute__((ext_vector_type(4))) float f32x4;
typedef __attribute__((ext_vector_type(4))) unsigned u32x4;

__device__ __forceinline__ ushort_t f2bf(float x) {
  union { float f; unsigned u; } v; v.f = x;
  unsigned r = v.u + 0x7fffu + ((v.u >> 16) & 1u);
  return (ushort_t)(r >> 16);
}
__device__ __forceinline__ float bf2f(ushort_t x) {
  union { unsigned u; float f; } v; v.u = ((unsigned)x) << 16; return v.f;
}
__device__ __forceinline__ float bfu2f(unsigned x) {
  union { unsigned u; float f; } v; v.u = x << 16; return v.f;
}
__device__ __forceinline__ float sigf(float x) { return 1.0f / (1.0f + __expf(-x)); }
__device__ __forceinline__ float tanh_f(float x) {
  float e = __expf(2.0f * x);
  return 1.0f - 2.0f / (e + 1.0f);
}
__device__ __forceinline__ float dot4(f32x4 a, f32x4 b) {
  return a.x * b.x + a.y * b.y + a.z * b.z + a.w * b.w;
}
// write-through store to device coherence point; readers cold-miss fresh data.
__device__ __forceinline__ void stg(float* p, float v) {
  __hip_atomic_store(p, v, __ATOMIC_RELAXED, __HIP_MEMORY_SCOPE_AGENT);
}
__device__ __forceinline__ void stg_u32(unsigned* p, unsigned v) {
  __hip_atomic_store(p, v, __ATOMIC_RELAXED, __HIP_MEMORY_SCOPE_AGENT);
}
__device__ __forceinline__ unsigned pollu(const unsigned* p) {
  return __hip_atomic_load(p, __ATOMIC_RELAXED, __HIP_MEMORY_SCOPE_AGENT);
}
__device__ __forceinline__ unsigned okq(u32x4 c) {
  return (unsigned)((c.x != SENTU) & (c.y != SENTU) & (c.z != SENTU) & (c.w != SENTU));
}
// IC-coherent, non-caching 16B load (sentinel polling without stale L2 fills).
__device__ __forceinline__ u32x4 ld1_ic(const unsigned* p) {
  u32x4 v;
  asm volatile("global_load_dwordx4 %0, %1, off sc0 sc1\n\ts_waitcnt vmcnt(0)"
               : "=&v"(v) : "v"(p) : "memory");
  return v;
}

// Slot barrier: NO atomics. Block i fire-and-forget stores epoch pc to its own
// 128B line; every block polls all slots with one wave (up to 3 slots/lane).
__device__ __forceinline__ void slot_barrier(unsigned* slots, int myslot, int nslots,
                                             unsigned pc) {
  asm volatile("s_waitcnt vmcnt(0)" ::: "memory");
  __syncthreads();
  if (threadIdx.x == 0)
    __hip_atomic_store(&slots[myslot * LINE], pc, __ATOMIC_RELAXED, __HIP_MEMORY_SCOPE_AGENT);
  if (threadIdx.x < 64) {
    const int i0 = threadIdx.x, i1 = threadIdx.x + 64, i2 = threadIdx.x + 128;
    for (;;) {
      unsigned v0 = pc, v1 = pc, v2 = pc;
      if (i0 < nslots) v0 = pollu(&slots[i0 * LINE]);
      if (i1 < nslots) v1 = pollu(&slots[i1 * LINE]);
      if (i2 < nslots) v2 = pollu(&slots[i2 * LINE]);
      if (__all((v0 >= pc) & (v1 >= pc) & (v2 >= pc))) break;
      __builtin_amdgcn_s_sleep(1);
    }
  }
  __syncthreads();
}

// ---------------- fused prologue: emb/wih cvt + Whh pack + source gather ----------------
__global__ __launch_bounds__(256) void prologue_kernel(const float* emb, const float* wih_f,
                                                       const float* wih_b, const float* whh_f,
                                                       const float* whh_b, const int* source,
                                                       ushort_t* emb_bf, ushort_t* wihf_bf,
                                                       ushort_t* wihb_bf, ushort_t* whh_pk,
                                                       ushort_t* xs_bf) {
  const int gtid = blockIdx.x * 256 + threadIdx.x;
  const int GSTR = 2048 * 256;
  for (int i = gtid; i < V_SZ * D_SZ; i += GSTR) emb_bf[i] = f2bf(emb[i]);
  for (int i = gtid; i < G4 * D_SZ; i += GSTR) wihf_bf[i] = f2bf(wih_f[i]);
  for (int i = gtid; i < G4 * D_SZ; i += GSTR) wihb_bf[i] = f2bf(wih_b[i]);
  for (int i = gtid; i < 2 * G4 * H_SZ; i += GSTR) {
    int col = i & 511;
    int p_g = i >> 9;
    int dir = p_g >> 11, p = p_g & 2047;
    int ub = p >> 6, g = (p >> 4) & 3, u = p & 15;
    const float* src = dir ? whh_b : whh_f;
    whh_pk[i] = f2bf(src[(size_t)(g * 512 + ub * 16 + u) * 512 + col]);
  }
  for (int i = gtid; i < S_SZ * B_SZ * D_SZ; i += GSTR) {
    int row = i >> 8, d = i & 255;
    int s = row >> 4, b = row & 15;
    int tok = source[b * S_SZ + s];
    xs_bf[i] = f2bf(emb[(size_t)tok * 256 + d]);
  }
}

// ---------------- MFMA helper: one wave computes a 16x64 tile of A(M,K) @ B(N,K)^T ------------
__device__ __forceinline__ void mfma_16x64(const ushort_t* A, const ushort_t* B_, int K,
                                           int m0, int n0, f32x4 acc[4]) {
  const int lane = threadIdx.x & 63;
  const int lr = lane & 15, kh = lane >> 4;
  const ushort_t* ap = A + (size_t)(m0 + lr) * K + kh * 8;
  const ushort_t* bp = B_ + (size_t)(n0 + lr) * K + kh * 8;
  for (int k0 = 0; k0 < K; k0 += 32) {
    bf16x8 av = *(const bf16x8*)(ap + k0);
#pragma unroll
    for (int s = 0; s < 4; ++s) {
      bf16x8 bv = *(const bf16x8*)(bp + (size_t)s * 16 * K + k0);
      acc[s] = __builtin_amdgcn_mfma_f32_16x16x32_bf16(av, bv, acc[s], 0, 0, 0);
    }
  }
}

// ---------------- enc-gates GEMM (both dirs via z): out[m][n] = A[m]·B[n] + bias[n] -----------
__global__ __launch_bounds__(256) void gemm_gates2(const ushort_t* A, const ushort_t* Bf,
                                                   const ushort_t* Bb, const float* bias_f,
                                                   const float* bias_b, float* out_f,
                                                   float* out_b) {
  int wave = threadIdx.x >> 6;
  int m0 = blockIdx.y * 16;
  int n0 = blockIdx.x * 256 + wave * 64;
  const ushort_t* Bm = blockIdx.z ? Bb : Bf;
  const float* bias = blockIdx.z ? bias_b : bias_f;
  float* out = blockIdx.z ? out_b : out_f;
  f32x4 acc[4] = {};
  mfma_16x64(A, Bm, D_SZ, m0, n0, acc);
  int lane = threadIdx.x & 63, lr = lane & 15, kh = lane >> 4;
#pragma unroll
  for (int s = 0; s < 4; ++s) {
    int n = n0 + s * 16 + lr;
    float bv = bias[n];
#pragma unroll
    for (int i = 0; i < 4; ++i) {
      int m = m0 + kh * 4 + i;
      out[(size_t)m * G4 + n] = acc[s][i] + bv;
    }
  }
}

// ---------------- enc_outs = ys_cat @ Wproj^T + bproj, out layout [b][s][h] ----------------
__global__ __launch_bounds__(256) void gemm_encout(const ushort_t* ys_cat, const ushort_t* wproj_bf,
                                                   const float* bproj, float* enc_outs) {
  int wave = threadIdx.x >> 6;
  int m0 = blockIdx.y * 16;
  int n0 = blockIdx.x * 256 + wave * 64;
  f32x4 acc[4] = {};
  mfma_16x64(ys_cat, wproj_bf, 2 * H_SZ, m0, n0, acc);
  int lane = threadIdx.x & 63, lr = lane & 15, kh = lane >> 4;
#pragma unroll
  for (int s = 0; s < 4; ++s) {
    int n = n0 + s * 16 + lr;
    float bv = bproj[n];
#pragma unroll
    for (int i = 0; i < 4; ++i) {
      int m = m0 + kh * 4 + i;
      int b = m & 15, si = m >> 4;
      enc_outs[((size_t)b * S_SZ + si) * H_SZ + n] = acc[s][i] + bv;
    }
  }
}

// ---------------- persistent bidirectional encoder LSTM + fused prep ----------------
// Blocks 0..63: round-8 recurrence (dir = blk>>5, ub = blk&31, IC slot barriers).
// Blocks 64..255 (192): independent prep pipeline (stage A -> 192-slot barrier -> stage B):
//   A: wo1/wihd/wo2t/wproj cvt, gather_tgt, wfp, wfused
//   B: pack_wdec (needs wfused), gemm_e2 (needs wo2t), dec-gates GEMM -> gxT (needs xt/wihd)
__global__ __launch_bounds__(256) void enc_kernel(
    const float* gx_f, const float* gx_b, const ushort_t* whh_pk, const int* src_len,
    unsigned* hbf_f, unsigned* hbf_b, unsigned* ys_cat_u32, float* h_final, float* c_final,
    unsigned* ctrs,
    // prep inputs/outputs
    const int* target, const ushort_t* emb_bf, ushort_t* xt_bf, const float* wo1,
    ushort_t* wo1_bf, const float* dwih, ushort_t* wihd_bf, const float* wo2,
    ushort_t* wo2t_bf, const float* wproj, ushort_t* wproj_bf, const float* wpgen, float* wfp,
    float* wfused, const float* dwhh, ushort_t* wdec_pk, ushort_t* e2_bf, const float* dbias,
    float* gxT) {
  __shared__ float gates_s[4 * 16 * 17];
  __shared__ float xr_s[256];
  const int blk = blockIdx.x, tid = threadIdx.x;

  if (blk >= 64) {
    // ---------------- prep pipeline ----------------
    const int pid = blk - 64;  // 0..191
    const int gtid = pid * 256 + tid;
    const int GSTR = 192 * 256;
    // stage A
    for (int i = gtid; i < 512 * 1024; i += GSTR) wo1_bf[i] = f2bf(wo1[i]);
    for (int i = gtid; i < 2048 * 256; i += GSTR) {
      int r = i >> 8, d = i & 255;
      wihd_bf[i] = f2bf(dwih[(size_t)r * 512 + d]);
    }
    for (int i = gtid; i < 512 * 256; i += GSTR) {
      int h2 = i >> 8, d2 = i & 255;
      wo2t_bf[i] = f2bf(wo2[(size_t)d2 * 512 + h2]);
    }
    for (int i = gtid; i < 512 * 1024; i += GSTR) wproj_bf[i] = f2bf(wproj[i]);
    for (int i = gtid; i < 51200; i += GSTR) {
      int r = i >> 5, e = i & 31;
      int tt = r >> 4, bb = r & 15;
      int tok = target[bb * T_SZ + tt];
      ((ushort8_t*)xt_bf)[i] = ((const ushort8_t*)emb_bf)[(size_t)tok * 32 + e];
    }
    for (int h2 = gtid; h2 < 512; h2 += GSTR) {
      float a = 0;
      for (int d = 0; d < 256; ++d) a += wpgen[1280 + d] * wo2[(size_t)d * 512 + h2];
      wfp[h2] = a;
    }
    for (int r = pid; r < 2048; r += 192) {
      xr_s[tid] = dwih[(size_t)r * 512 + 256 + tid];
      __syncthreads();
      float a0 = 0, a1 = 0;
      for (int d = 0; d < 256; ++d) {
        float x = xr_s[d];
        a0 += x * wo2[(size_t)d * 512 + tid];
        a1 += x * wo2[(size_t)d * 512 + tid + 256];
      }
      wfused[(size_t)r * 512 + tid] = a0;
      wfused[(size_t)r * 512 + tid + 256] = a1;
      __syncthreads();
    }
    slot_barrier(ctrs + 2048, pid, 192, 1u);
    // stage B
    for (int i = gtid; i < 2048 * 1024; i += GSTR) {
      int col = i & 1023, p = i >> 10;
      int ub2 = p >> 4, g2 = (p >> 2) & 3, u2 = p & 3;
      int row = g2 * 512 + ub2 * 4 + u2;
      float v = (col < 512) ? dwhh[(size_t)row * 512 + col]
                            : wfused[(size_t)row * 512 + (col - 512)];
      wdec_pk[i] = f2bf(v);
    }
    for (int q = pid; q < 4000; q += 192) {
      int mt = q >> 1, xt2 = q & 1;
      int wave = tid >> 6;
      int m0 = mt * 16, n0 = xt2 * 256 + wave * 64;
      f32x4 acc[4] = {};
      mfma_16x64(emb_bf, wo2t_bf, 256, m0, n0, acc);
      int lane2 = tid & 63, lr2 = lane2 & 15, kh2 = lane2 >> 4;
#pragma unroll
      for (int s = 0; s < 4; ++s) {
        int n = n0 + s * 16 + lr2;
#pragma unroll
        for (int i = 0; i < 4; ++i) {
          int m = m0 + kh2 * 4 + i;
          e2_bf[(size_t)m * 512 + n] = f2bf(acc[s][i]);
        }
      }
    }
    // dec-gates GEMM: gxT[(t*2048 + n)*16 + b] = xt @ Wihd^T + dbias (direct transposed write)
    for (int q = pid; q < 800; q += 192) {
      int mt = q >> 3, nt = q & 7;  // mt = decoder step t, nt = 256-col tile
      int wave = tid >> 6;
      int m0 = mt * 16, n0 = nt * 256 + wave * 64;
      f32x4 acc[4] = {};
      mfma_16x64(xt_bf, wihd_bf, 256, m0, n0, acc);
      int lane2 = tid & 63, lr2 = lane2 & 15, kh2 = lane2 >> 4;
#pragma unroll
      for (int s = 0; s < 4; ++s) {
        int n = n0 + s * 16 + lr2;
        float bv = dbias[n];
#pragma unroll
        for (int i = 0; i < 4; ++i) {
          int b = kh2 * 4 + i;
          gxT[((size_t)mt * G4 + n) * 16 + b] = acc[s][i] + bv;
        }
      }
    }
    return;
  }

  // ---------------- recurrence (round-8, IC slot barriers) ----------------
  const int dir = blk >> 5, ub = blk & 31, j0 = ub * 16;
  const int g = tid >> 6, lane = tid & 63, lr = lane & 15, kh = lane >> 4;
  const float* gx = dir ? gx_b : gx_f;
  unsigned* hb = dir ? hbf_b : hbf_f;
  unsigned* slots = ctrs + dir * 1024;
  const ushort_t* wrow =
      whh_pk + (size_t)(((dir * 32 + ub) * 4 + g) * 16 + lr) * 512 + kh * 8;
  const int bc = tid >> 4, uc = tid & 15;
  const int len_b = src_len[bc];
  float c_reg = 0.0f, h_reg = 0.0f;

  int maxlen;
  {
    int v = src_len[lane & 15];
    v = max(v, __shfl_xor(v, 1));
    v = max(v, __shfl_xor(v, 2));
    v = max(v, __shfl_xor(v, 4));
    v = max(v, __shfl_xor(v, 8));
    maxlen = v;
  }
  for (int i = tid; i < (S_SZ - maxlen) * 128; i += 256) {
    int s = maxlen + (i >> 7);
    int r = i & 127;
    int bb = r >> 3, k = r & 7;
    ys_cat_u32[(size_t)(s * 16 + bb) * 512 + dir * 256 + (j0 >> 1) + k] = 0u;
  }

  float gxa[4];
  {
    const int s0 = dir ? (maxlen - 1) : 0;
    const float* g0 = gx + (size_t)s0 * (16 * 2048) + g * 512 + j0 + lr;
#pragma unroll
    for (int i = 0; i < 4; ++i) gxa[i] = g0[(size_t)(kh * 4 + i) * 2048];
  }

  for (int t = 0; t < maxlen; ++t) {
    const int s_pos = dir ? (maxlen - 1 - t) : t;
    float gxn[4] = {0.f, 0.f, 0.f, 0.f};
    if (t + 1 < maxlen) {
      const int sn = dir ? (maxlen - 2 - t) : (t + 1);
      const float* gn = gx + (size_t)sn * (16 * 2048) + g * 512 + j0 + lr;
#pragma unroll
      for (int i = 0; i < 4; ++i) gxn[i] = gn[(size_t)(kh * 4 + i) * 2048];
    }
    f32x4 acc = {0.f, 0.f, 0.f, 0.f};
    const ushort_t* ap = (const ushort_t*)(hb + (size_t)t * 4096) + lr * 512 + kh * 8;
#pragma unroll
    for (int k0 = 0; k0 < 512; k0 += 32)
      acc = __builtin_amdgcn_mfma_f32_16x16x32_bf16(*(const bf16x8*)(ap + k0),
                                                    *(const bf16x8*)(wrow + k0), acc, 0, 0, 0);
#pragma unroll
    for (int i = 0; i < 4; ++i)
      gates_s[(g * 16 + lr) * 17 + kh * 4 + i] = acc[i] + gxa[i];
    __syncthreads();
    float gi = gates_s[uc * 17 + bc];
    float gf = gates_s[(16 + uc) * 17 + bc];
    float gg = gates_s[(32 + uc) * 17 + bc];
    float go = gates_s[(48 + uc) * 17 + bc];
    bool msk = s_pos < len_b;
    float cn = sigf(gf) * c_reg + sigf(gi) * tanh_f(gg);
    float hn = sigf(go) * tanh_f(cn);
    float hout = msk ? hn : h_reg;
    if (msk) c_reg = cn;
    h_reg = hout;
    unsigned hbits = (unsigned)f2bf(hout);
    unsigned hpart = __shfl_xor(hbits, 1);
    unsigned ybits = msk ? (unsigned)f2bf(hn) : 0u;
    unsigned ypart = __shfl_xor(ybits, 1);
    if ((uc & 1) == 0) {
      stg_u32(&hb[(size_t)(t + 1) * 4096 + bc * 256 + ((j0 + uc) >> 1)], hbits | (hpart << 16));
      ys_cat_u32[(size_t)(s_pos * 16 + bc) * 512 + dir * 256 + ((j0 + uc) >> 1)] =
          ybits | (ypart << 16);
    }
    if (t == maxlen - 1) {
      h_final[dir * 8192 + bc * 512 + j0 + uc] = hout;
      c_final[dir * 8192 + bc * 512 + j0 + uc] = c_reg;
    }
    if (t + 1 < maxlen) slot_barrier(slots, ub, 32, (unsigned)(t + 1));
#pragma unroll
    for (int i = 0; i < 4; ++i) gxa[i] = gxn[i];
  }
}

// ---------------- seq_mean ----------------
__global__ __launch_bounds__(256) void seqmean_kernel(const float* enc_outs, const int* src_len,
                                                      float* seq_mean) {
  int b = blockIdx.x >> 1;
  int j = (blockIdx.x & 1) * 256 + threadIdx.x;
  int L = src_len[b];
  float a = 0;
  for (int s = 0; s < L; ++s) a += enc_outs[((size_t)b * S_SZ + s) * H_SZ + j];
  seq_mean[b * 512 + j] = a / (float)L;
}

// ---------------- dec state init: h (bf16 packed) + c (f32) ----------------
__global__ __launch_bounds__(256) void init_state_kernel(const float* h_final, const float* c_final,
                                                         const float* w2h, const float* b2h,
                                                         const float* w2c, const float* b2c,
                                                         unsigned* h_u32, float* c_init) {
  int gid = blockIdx.x * 256 + threadIdx.x;  // 16384
  int half = gid >> 13;
  int idx = gid & 8191;
  int b = idx >> 9, j = idx & 511;
  const float* src = half ? c_final : h_final;
  const float* w = (half ? w2c : w2h) + (size_t)j * 1024;
  float acc = (half ? b2c : b2h)[j];
  const f32x4* s0 = (const f32x4*)(src + b * 512);
  const f32x4* s1 = (const f32x4*)(src + 8192 + b * 512);
  const f32x4* w0 = (const f32x4*)w;
  const f32x4* w1 = w0 + 128;
  float a = 0;
  for (int k = 0; k < 128; ++k) a += dot4(s0[k], w0[k]);
  for (int k = 0; k < 128; ++k) a += dot4(s1[k], w1[k]);
  acc += a;
  if (half) {
    c_init[idx] = acc;
  } else {
    unsigned bits = (unsigned)f2bf(acc);
    unsigned pb2 = __shfl_xor(bits, 1);
    if ((j & 1) == 0) h_u32[b * 256 + (j >> 1)] = bits | (pb2 << 16);
  }
}

// ---------------- tmp0 = tanh([dec_h | seq_mean] @ Wo1^T + bo1) -> tmp slot 0 (bf16) ---------
__global__ __launch_bounds__(256) void tmp0_kernel(const unsigned* h0_u32, const float* seq_mean,
                                                   const float* wo1, const float* bo1,
                                                   unsigned* tmp_u32) {
  int gid = blockIdx.x * 256 + threadIdx.x;  // 8192
  int b = gid >> 9, j = gid & 511;
  const f32x4* x1 = (const f32x4*)(seq_mean + b * 512);
  const f32x4* w0 = (const f32x4*)(wo1 + (size_t)j * 1024);
  const f32x4* w1 = w0 + 128;
  float a = bo1[j];
  float p = 0;
  const ushort_t* h0 = (const ushort_t*)(h0_u32) + b * 512;
  for (int k = 0; k < 128; ++k) {
    f32x4 hv = {bf2f(h0[k * 4]), bf2f(h0[k * 4 + 1]), bf2f(h0[k * 4 + 2]), bf2f(h0[k * 4 + 3])};
    p += dot4(hv, w0[k]);
  }
  for (int k = 0; k < 128; ++k) p += dot4(x1[k], w1[k]);
  float tv = tanh_f(a + p);
  unsigned bits = (unsigned)f2bf(tv);
  unsigned pb2 = __shfl_xor(bits, 1);
  if ((j & 1) == 0) tmp_u32[b * 256 + (j >> 1)] = bits | (pb2 << 16);
}

// ---------------- persistent decoder (round-8 core) + fused logits ----------------
// Blocks 0..127: PA -> global slot-barrier -> PB -> 8-slot group barrier -> PC -> global.
// Block 128: leader — sentinel-polls each step's tmp row (non-caching sc0 sc1), then tags.
// Blocks 129..253: logits workers — per t, wait tag, compute one 16x256 tile of
//   logits = tmp @ E2^T into d_out.
__global__ __launch_bounds__(256) void dec_kernel(
    const ushort_t* xt_bf, const int* src_len, const ushort_t* wdec_pk,
    const float* wpgen, const float* bpgen, const float* wfp, const ushort_t* wo1_bf,
    const float* bo1, const float* enc_outs, const float* gxT, unsigned* h_u32,
    const float* c_init, unsigned* tmp_u32, float* ctx_part, float* z_part, float* zinv,
    float* pgen_o, float* pexp, unsigned* ctrs, const ushort_t* e2_bf, float* out) {
  __shared__ ushort_t ec_s[50 * 512];  // 51.2 KB enc chunk (bf16)
  __shared__ float part_s[4 * 16 * 17];
  __shared__ f32x4 smem4[272];  // h_s(512) + ctx_s(512) + pad
  __shared__ float red_s[8];
  __shared__ float p_s[64];
  float* sm = (float*)smem4;
  unsigned* gslots = ctrs + 8192;   // 128 slot lines, global dec barrier

  const int blk = blockIdx.x, tid = threadIdx.x;

  if (blk >= 128) {
    // ---------------- fused logits ----------------
    const int sp = blk - 128;
    unsigned* tags = ctrs + 16384;  // 100 lines
    if (sp == 0) {
      for (int t = 0; t < T_SZ; ++t) {
        if (tid < 64) {
          const unsigned* hp = tmp_u32 + (size_t)(t + 1) * 4096 + tid * 64;
          for (;;) {
            unsigned ok = 1;
#pragma unroll
            for (int k = 0; k < 16; ++k) ok &= okq(ld1_ic(hp + k * 4));
            if (__all((int)ok)) break;
            __builtin_amdgcn_s_sleep(8);
          }
          if (tid == 0) stg_u32(&tags[t * 32], 1u);
        }
        __syncthreads();
      }
    } else if (sp <= 125) {
      const ushort_t* tmp_bf2 = (const ushort_t*)(tmp_u32 + 4096);
      const int wave = tid >> 6;
      const int n0 = (sp - 1) * 256 + wave * 64;
      const int lane2 = tid & 63, lr2 = lane2 & 15, kh2 = lane2 >> 4;
      for (int t = 0; t < T_SZ; ++t) {
        if (tid < 64) {
          while (pollu(&tags[t * 32]) == 0u) __builtin_amdgcn_s_sleep(4);
        }
        __syncthreads();
        f32x4 acc[4] = {};
        mfma_16x64(tmp_bf2, e2_bf, 512, t * 16, n0, acc);
#pragma unroll
        for (int s = 0; s < 4; ++s) {
          int n = n0 + s * 16 + lr2;
#pragma unroll
          for (int i = 0; i < 4; ++i) {
            int m = t * 16 + kh2 * 4 + i;
            out[(size_t)m * VX + n] = acc[s][i];
          }
        }
      }
    }
    return;
  }

  // ---------------- decoder core (round-8) ----------------
  const int w = tid >> 6, lane = tid & 63, lr = lane & 15, kh = lane >> 4;
  const int j0 = blk * 4;
  const ushort_t* wrow = wdec_pk + (size_t)(blk * 16 + lr) * 1024 + w * 256 + kh * 8;
  const int b_c = (tid >> 2) & 15, u_c = tid & 3;  // cell roles (tid<64)
  float c_reg = (tid < 64) ? c_init[b_c * 512 + j0 + u_c] : 0.0f;
  const int b_pb = blk >> 3, ch = blk & 7, s0c = ch * 50;
  const int len_pb = src_len[b_pb];
  const int nc = ch;
  unsigned* grslots = ctrs + 12288 + b_pb * 256;  // 8 slot lines per batch group
  unsigned gpc = 0;

  {
    const f32x4* ebase = (const f32x4*)(enc_outs + ((size_t)b_pb * S_SZ + s0c) * H_SZ);
    unsigned* dst = (unsigned*)ec_s;
    for (int i = tid; i < 6400; i += 256) {
      f32x4 v = ebase[i];
      dst[2 * i] = (unsigned)f2bf(v.x) | ((unsigned)f2bf(v.y) << 16);
      dst[2 * i + 1] = (unsigned)f2bf(v.z) | ((unsigned)f2bf(v.w) << 16);
    }
  }

  float gxa[4] = {0.f, 0.f, 0.f, 0.f};
  if (tid < 64) {
#pragma unroll
    for (int g2 = 0; g2 < 4; ++g2)
      gxa[g2] = gxT[((size_t)(g2 * 512 + j0 + u_c)) * 16 + b_c];
  }

  for (int t = 0; t < T_SZ; ++t) {
    // ---------- PA: gates via MFMA (K=1024 split over 4 waves) ----------
    {
      f32x4 acc = {0.f, 0.f, 0.f, 0.f};
      const unsigned* asrc = (w < 2) ? (h_u32 + (size_t)t * 4096) : (tmp_u32 + (size_t)t * 4096);
      const ushort_t* ap = (const ushort_t*)asrc + lr * 512 + (w & 1) * 256 + kh * 8;
#pragma unroll
      for (int k0 = 0; k0 < 256; k0 += 32)
        acc = __builtin_amdgcn_mfma_f32_16x16x32_bf16(*(const bf16x8*)(ap + k0),
                                                      *(const bf16x8*)(wrow + k0), acc, 0, 0, 0);
#pragma unroll
      for (int i = 0; i < 4; ++i) part_s[(w * 16 + lr) * 17 + kh * 4 + i] = acc[i];
      __syncthreads();
      if (tid < 64) {
        float gt[4];
#pragma unroll
        for (int g2 = 0; g2 < 4; ++g2) {
          int p = g2 * 4 + u_c;
          float a = gxa[g2];
#pragma unroll
          for (int w2 = 0; w2 < 4; ++w2) a += part_s[(w2 * 16 + p) * 17 + b_c];
          gt[g2] = a;
        }
        float cn = sigf(gt[1]) * c_reg + sigf(gt[0]) * tanh_f(gt[2]);
        c_reg = cn;
        float hn = sigf(gt[3]) * tanh_f(cn);
        unsigned bits = (unsigned)f2bf(hn);
        unsigned pb2 = __shfl_xor(bits, 1);
        if ((u_c & 1) == 0)
          stg_u32(&h_u32[(size_t)(t + 1) * 4096 + b_c * 256 + ((j0 + u_c) >> 1)],
                  bits | (pb2 << 16));
      }
    }
    slot_barrier(gslots, blk, 128, ++gpc);
    // ---------- PB: scores + partial ctx from LDS chunk ----------
    {
      if (tid < 64 && t + 1 < T_SZ) {
#pragma unroll
        for (int g2 = 0; g2 < 4; ++g2)
          gxa[g2] = gxT[((size_t)(t + 1) * G4 + g2 * 512 + j0 + u_c) * 16 + b_c];
      }
      if (tid < 128) {
        unsigned v0 = h_u32[(size_t)(t + 1) * 4096 + b_pb * 256 + tid * 2];
        unsigned v1 = h_u32[(size_t)(t + 1) * 4096 + b_pb * 256 + tid * 2 + 1];
        f32x4 hv = {bfu2f(v0 & 0xffffu), bfu2f(v0 >> 16), bfu2f(v1 & 0xffffu), bfu2f(v1 >> 16)};
        ((f32x4*)sm)[tid] = hv;
      }
      __syncthreads();
      int st = tid >> 2, kq = tid & 3;
      if (st < 50) {
        const ushort8_t* er = (const ushort8_t*)(ec_s + st * 512) + kq * 16;
        const f32x4* hr = (const f32x4*)sm + kq * 32;
        float sc = 0;
#pragma unroll 4
        for (int k = 0; k < 16; ++k) {
          ushort8_t w8 = er[k];
          f32x4 w0 = {bf2f(w8[0]), bf2f(w8[1]), bf2f(w8[2]), bf2f(w8[3])};
          f32x4 w1 = {bf2f(w8[4]), bf2f(w8[5]), bf2f(w8[6]), bf2f(w8[7])};
          sc += dot4(hr[2 * k], w0) + dot4(hr[2 * k + 1], w1);
        }
        sc += __shfl_xor(sc, 1);
        sc += __shfl_xor(sc, 2);
        if (kq == 0) {
          int s_abs = s0c + st;
          float p = (s_abs < len_pb) ? __expf(sc) : 0.0f;
          p_s[st] = p;
          pexp[((size_t)t * 16 + b_pb) * S_SZ + s_abs] = p;
        }
      }
      __syncthreads();
      if (tid == 0) {
        float z = 0;
        for (int s = 0; s < 50; ++s) z += p_s[s];
        stg(&z_part[((size_t)t * 16 + b_pb) * 8 + ch], z);
      }
      float a0 = 0, a1 = 0;
      for (int s = 0; s < 50; ++s) {
        float p = p_s[s];
        a0 += p * bf2f(ec_s[s * 512 + tid]);
        a1 += p * bf2f(ec_s[s * 512 + tid + 256]);
      }
      float* cp = ctx_part + (((size_t)t * 16 + b_pb) * 8 + ch) * 512;
      stg(&cp[tid], a0);
      stg(&cp[tid + 256], a1);
    }
    slot_barrier(grslots, ch, 8, (unsigned)(t + 1));
    // ---------- PC: combine ctx + pgen + tmp (h staged in sm by PB) ----------
    {
      float* h_s = sm;
      float* ctx_s = sm + 512;
      const float* zp = z_part + ((size_t)t * 16 + b_pb) * 8;
      float z = 0;
#pragma unroll
      for (int c2 = 0; c2 < 8; ++c2) z += zp[c2];
      float inv = 1.0f / z;
      const float* cpb = ctx_part + ((size_t)t * 16 + b_pb) * 8 * 512;
      float c0 = 0, c1 = 0;
#pragma unroll
      for (int c2 = 0; c2 < 8; ++c2) {
        c0 += cpb[c2 * 512 + tid];
        c1 += cpb[c2 * 512 + tid + 256];
      }
      ctx_s[tid] = c0 * inv;
      ctx_s[tid + 256] = c1 * inv;
      __syncthreads();
      const ushort_t* tmpp = (const ushort_t*)(tmp_u32 + (size_t)t * 4096) + b_pb * 512;
      float tp0 = bf2f(tmpp[tid]);
      float tp1 = bf2f(tmpp[tid + 256]);
      float xe = bf2f(xt_bf[((size_t)t * 16 + b_pb) * 256 + tid]);
      float pg = wpgen[tid] * ctx_s[tid] + wpgen[tid + 256] * ctx_s[tid + 256] +
                 wpgen[512 + tid] * h_s[tid] + wpgen[512 + tid + 256] * h_s[tid + 256] +
                 wpgen[1024 + tid] * xe + wfp[tid] * tp0 + wfp[tid + 256] * tp1;
#pragma unroll
      for (int o = 32; o; o >>= 1) pg += __shfl_xor(pg, o);
      if (lane == 0) red_s[w] = pg;
      __syncthreads();
      if (nc == 0 && tid == 0) {
        pgen_o[t * 16 + b_pb] = sigf(red_s[0] + red_s[1] + red_s[2] + red_s[3] + bpgen[0]);
        zinv[t * 16 + b_pb] = inv;
      }
      int nidx = tid >> 2, kq = tid & 3;
      int n = nc * 64 + nidx;
      const ushort8_t* wrp = (const ushort8_t*)(wo1_bf + (size_t)n * 1024) + kq * 32;
      const f32x4* xr2 =
          (kq < 2) ? ((const f32x4*)h_s + kq * 64) : ((const f32x4*)ctx_s + (kq - 2) * 64);
      float a = 0;
#pragma unroll 4
      for (int k = 0; k < 32; ++k) {
        ushort8_t w8 = wrp[k];
        f32x4 w0 = {bf2f(w8[0]), bf2f(w8[1]), bf2f(w8[2]), bf2f(w8[3])};
        f32x4 w1 = {bf2f(w8[4]), bf2f(w8[5]), bf2f(w8[6]), bf2f(w8[7])};
        a += dot4(xr2[2 * k], w0) + dot4(xr2[2 * k + 1], w1);
      }
      a += __shfl_xor(a, 1);
      a += __shfl_xor(a, 2);
      float tv = tanh_f(a + bo1[n]);
      unsigned bits = (unsigned)f2bf(tv);
      unsigned pbits = __shfl_xor(bits, 4);
      if (kq == 0 && (nidx & 1) == 0)
        stg_u32(&tmp_u32[(size_t)(t + 1) * 4096 + b_pb * 256 + ((nc * 64 + nidx) >> 1)],
                bits | (pbits << 16));
    }
    if (t + 1 < T_SZ) slot_barrier(gslots, blk, 128, ++gpc);
  }
}

// ---------------- per (t,b) row softmax + copy-scatter + log ----------------
__global__ __launch_bounds__(1024) void finalize_kernel(float* out, const float* pexp,
                                                        const float* zinv, const float* pgen_i,
                                                        const int* src_ext) {
  __shared__ float scat[VX];
  __shared__ float red[64];
  const int row = blockIdx.x;
  const int b = row & 15;
  const int tid = threadIdx.x;
  for (int i = tid; i < VX; i += 1024) scat[i] = 0.0f;
  __syncthreads();
  const float pg = pgen_i[row];
  const float inv = zinv[row];
  if (tid < S_SZ) {
    float v = (1.0f - pg) * pexp[(size_t)row * S_SZ + tid] * inv;
    int col = src_ext[b * S_SZ + tid];
    atomicAdd(&scat[col], v);
  }
  float* orow = out + (size_t)row * VX;
  float l[32];
  float mx = -3.4e38f;
#pragma unroll
  for (int i2 = 0; i2 < 32; ++i2) {
    int col = tid + (i2 << 10);
    l[i2] = (col < V_SZ) ? orow[col] : -3.4e38f;
    mx = fmaxf(mx, l[i2]);
  }
#pragma unroll
  for (int o = 32; o; o >>= 1) mx = fmaxf(mx, __shfl_xor(mx, o));
  if ((tid & 63) == 0) red[16 + (tid >> 6)] = mx;
  __syncthreads();
  if (tid == 0) {
    float m2 = red[16];
    for (int w = 1; w < 16; ++w) m2 = fmaxf(m2, red[16 + w]);
    red[0] = m2;
  }
  __syncthreads();
  const float gmx = red[0];
  float se = 0.0f;
#pragma unroll
  for (int i2 = 0; i2 < 32; ++i2) {
    int col = tid + (i2 << 10);
    if (col < V_SZ) {
      l[i2] = __expf(l[i2] - gmx);
      se += l[i2];
    }
  }
#pragma unroll
  for (int o = 32; o; o >>= 1) se += __shfl_xor(se, o);
  if ((tid & 63) == 0) red[32 + (tid >> 6)] = se;
  __syncthreads();
  if (tid == 0) {
    float s2 = 0;
    for (int w = 0; w < 16; ++w) s2 += red[32 + w];
    red[1] = s2;
  }
  __syncthreads();
  const float scale = pg / red[1];
#pragma unroll
  for (int i2 = 0; i2 < 32; ++i2) {
    int col = tid + (i2 << 10);
    if (col < VX) {
      float base = (col < V_SZ) ? l[i2] * scale : 0.0f;
      orow[col] = __logf(base + scat[col] + 1e-20f);
    }
  }
}

extern "C" void kernel_launch(void* const* d_in, const int* in_sizes, int n_in, void* d_out,
                              int out_size, void* d_ws, size_t ws_size, hipStream_t stream) {
  (void)in_sizes; (void)n_in; (void)out_size; (void)ws_size;
  const int* source = (const int*)d_in[0];
  const int* source_ext = (const int*)d_in[1];
  const int* source_len = (const int*)d_in[2];
  const int* target = (const int*)d_in[3];
  const float* emb = (const float*)d_in[4];
  const float* wih_f = (const float*)d_in[5];
  const float* whh_f = (const float*)d_in[6];
  const float* b_f = (const float*)d_in[7];
  const float* wih_b = (const float*)d_in[8];
  const float* whh_b = (const float*)d_in[9];
  const float* b_b = (const float*)d_in[10];
  const float* wproj = (const float*)d_in[11];
  const float* bproj = (const float*)d_in[12];
  const float* w2h = (const float*)d_in[13];
  const float* b2h = (const float*)d_in[14];
  const float* w2c = (const float*)d_in[15];
  const float* b2c = (const float*)d_in[16];
  const float* wo1 = (const float*)d_in[17];
  const float* bo1 = (const float*)d_in[18];
  const float* wo2 = (const float*)d_in[19];
  const float* dwih = (const float*)d_in[20];
  const float* dwhh = (const float*)d_in[21];
  const float* dbias = (const float*)d_in[22];
  const float* wpgen = (const float*)d_in[23];
  const float* bpgen = (const float*)d_in[24];
  float* out = (float*)d_out;

  size_t off = 0;
  char* wsb = (char*)d_ws;
  auto alloc = [&](size_t bytes) -> void* {
    void* p = wsb + off;
    off += (bytes + 255) & ~(size_t)255;
    return p;
  };
  // ctrs words: [0..1024) encf slots, [1024..2048) encb, [2048..8192) prep slots(192),
  // [8192..12288) dec global slots(128), [12288..16384) dec group slots, [16384..19584) tags
  unsigned* ctrs = (unsigned*)alloc(80 * 1024);
  ushort_t* emb_bf = (ushort_t*)alloc((size_t)V_SZ * D_SZ * 2);
  ushort_t* wihf_bf = (ushort_t*)alloc((size_t)G4 * D_SZ * 2);
  ushort_t* wihb_bf = (ushort_t*)alloc((size_t)G4 * D_SZ * 2);
  ushort_t* wihd_bf = (ushort_t*)alloc((size_t)G4 * D_SZ * 2);
  ushort_t* wproj_bf = (ushort_t*)alloc((size_t)H_SZ * 2 * H_SZ * 2);
  ushort_t* wo2t_bf = (ushort_t*)alloc((size_t)H_SZ * D_SZ * 2);
  ushort_t* wo1_bf = (ushort_t*)alloc((size_t)H_SZ * 1024 * 2);
  float* wfused = (float*)alloc((size_t)G4 * H_SZ * 4);
  float* wfp = (float*)alloc(512 * 4);
  ushort_t* whh_pk = (ushort_t*)alloc((size_t)2 * G4 * H_SZ * 2);
  ushort_t* wdec_pk = (ushort_t*)alloc((size_t)G4 * 1024 * 2);
  ushort_t* xs_bf = (ushort_t*)alloc((size_t)S_SZ * B_SZ * D_SZ * 2);
  ushort_t* xt_bf = (ushort_t*)alloc((size_t)T_SZ * B_SZ * D_SZ * 2);
  ushort_t* e2_bf = (ushort_t*)alloc((size_t)V_SZ * H_SZ * 2);  // dedicated (32.8 MB)
  float* gxT = (float*)alloc((size_t)T_SZ * B_SZ * G4 * 4);     // dedicated (13.1 MB)
  float* gx_f = (float*)alloc((size_t)S_SZ * B_SZ * G4 * 4);
  float* gx_b = (float*)alloc((size_t)S_SZ * B_SZ * G4 * 4);  // aliased post-enc by ctx_part
  unsigned* hbf_f = (unsigned*)alloc((size_t)(S_SZ + 1) * 4096 * 4);
  unsigned* hbf_b = (unsigned*)alloc((size_t)(S_SZ + 1) * 4096 * 4);
  unsigned* ys_cat_u32 = (unsigned*)alloc((size_t)S_SZ * B_SZ * 512 * 4);
  float* h_final = (float*)alloc((size_t)2 * B_SZ * H_SZ * 4);
  float* c_final = (float*)alloc((size_t)2 * B_SZ * H_SZ * 4);
  float* enc_outs = (float*)alloc((size_t)B_SZ * S_SZ * H_SZ * 4);
  float* seq_mean = (float*)alloc((size_t)B_SZ * H_SZ * 4);
  unsigned* h_u32 = (unsigned*)alloc((size_t)(T_SZ + 1) * 4096 * 4);
  float* c_init = (float*)alloc((size_t)B_SZ * H_SZ * 4);
  unsigned* tmp_u32 = (unsigned*)alloc((size_t)(T_SZ + 1) * 4096 * 4);
  float* z_part = (float*)alloc((size_t)T_SZ * B_SZ * 8 * 4);
  float* zinv = (float*)alloc((size_t)T_SZ * B_SZ * 4);
  float* pgen_b = (float*)alloc((size_t)T_SZ * B_SZ * 4);
  float* pexp = (float*)alloc((size_t)T_SZ * B_SZ * S_SZ * 4);
  // alias into dead-after-encoder gx_b
  float* ctx_part = gx_b + (size_t)3276800;              // 6,553,600 floats

  hipMemsetAsync(ctrs, 0, 80 * 1024, stream);            // slots + tags
  hipMemsetAsync(tmp_u32, 0xFF, (size_t)(T_SZ + 1) * 4096 * 4, stream);  // sentinel (leader)
  hipMemsetAsync(hbf_f, 0, 4096 * 4, stream);            // enc h slot 0 (dir f)
  hipMemsetAsync(hbf_b, 0, 4096 * 4, stream);            // enc h slot 0 (dir b)

  prologue_kernel<<<2048, 256, 0, stream>>>(emb, wih_f, wih_b, whh_f, whh_b, source, emb_bf,
                                            wihf_bf, wihb_bf, whh_pk, xs_bf);
  gemm_gates2<<<dim3(8, 400, 2), 256, 0, stream>>>(xs_bf, wihf_bf, wihb_bf, b_f, b_b, gx_f, gx_b);
  enc_kernel<<<256, 256, 0, stream>>>(gx_f, gx_b, whh_pk, source_len, hbf_f, hbf_b, ys_cat_u32,
                                      h_final, c_final, ctrs, target, emb_bf, xt_bf, wo1, wo1_bf,
                                      dwih, wihd_bf, wo2, wo2t_bf, wproj, wproj_bf, wpgen, wfp,
                                      wfused, dwhh, wdec_pk, e2_bf, dbias, gxT);
  gemm_encout<<<dim3(2, 400), 256, 0, stream>>>((const ushort_t*)ys_cat_u32, wproj_bf, bproj,
                                                enc_outs);
  seqmean_kernel<<<32, 256, 0, stream>>>(enc_outs, source_len, seq_mean);
  init_state_kernel<<<64, 256, 0, stream>>>(h_final, c_final, w2h, b2h, w2c, b2c, h_u32, c_init);
  tmp0_kernel<<<32, 256, 0, stream>>>(h_u32, seq_mean, wo1, bo1, tmp_u32);
  dec_kernel<<<256, 256, 0, stream>>>(xt_bf, source_len, wdec_pk, wpgen, bpgen, wfp, wo1_bf, bo1,
                                      enc_outs, gxT, h_u32, c_init, tmp_u32, ctx_part, z_part,
                                      zinv, pgen_b, pexp, ctrs, e2_bf, out);
  finalize_kernel<<<1600, 1024, 0, stream>>>(out, pexp, zinv, pgen_b, source_ext);
}